// Round 2
// baseline (534.757 us; speedup 1.0000x reference)
//
#include <hip/hip_runtime.h>
#include <stdint.h>

#define DEPTHC 2
#define DIMC   512
#define FFC    2048
#define INNERC 32
#define VOCABC 8192
#define BC     2
#define LC     512
#define NTOK   1024   // B*L

typedef _Float16 f16;
typedef __attribute__((ext_vector_type(8))) _Float16 f16x8;
typedef __attribute__((ext_vector_type(4))) float f32x4;

__device__ __forceinline__ float2 cmul2(float2 a, float2 b){
    return make_float2(a.x*b.x - a.y*b.y, a.x*b.y + a.y*b.x);
}
__device__ __forceinline__ float2 cadd2(float2 a, float2 b){
    return make_float2(a.x + b.x, a.y + b.y);
}

__device__ __forceinline__ void gl_lds16(const void* g, void* l){
    __builtin_amdgcn_global_load_lds(
        (const __attribute__((address_space(1))) unsigned int*)g,
        (__attribute__((address_space(3))) unsigned int*)l, 16, 0, 0);
}

// ---------------- fused fp32 -> fp16 convert for 5 tensors ----------------
__global__ void k_f2h5(const float* s0, const float* s1, const float* s2,
                       const float* s3, const float* s4,
                       f16* d0, f16* d1, f16* d2, f16* d3, f16* d4,
                       int n0, int n1, int n2, int n3, int n4){
    const float* s; f16* d; int n;
    switch (blockIdx.y){
        case 0: s = s0; d = d0; n = n0; break;
        case 1: s = s1; d = d1; n = n1; break;
        case 2: s = s2; d = d2; n = n2; break;
        case 3: s = s3; d = d3; n = n3; break;
        default: s = s4; d = d4; n = n4; break;
    }
    int i = (blockIdx.x * 256 + threadIdx.x) * 4;
    if (i >= n) return;
    float4 v = *(const float4*)(s + i);
    union { f16 h[4]; float2 f2; } u;
    u.h[0] = (f16)v.x; u.h[1] = (f16)v.y; u.h[2] = (f16)v.z; u.h[3] = (f16)v.w;
    *(float2*)(d + i) = u.f2;
}

// ---------------- complex 32x32 inverse: single-wave fp64 Gauss-Jordan ----------------
// Lane c owns column c of the augmented [M | I] (64 cols). Fully unrolled so all
// register-array indices are static; cross-lane via __shfl, zero barriers/LDS.
__global__ __launch_bounds__(64) void k_inv(const float* __restrict__ v_re,
                                            const float* __restrict__ v_im,
                                            float2* __restrict__ vinv){
    int d = blockIdx.x;
    int c = threadIdx.x;  // 0..63
    double Mr[32], Mi[32];
#pragma unroll
    for (int r = 0; r < 32; ++r){
        if (c < 32){ Mr[r] = (double)v_re[d*1024 + r*32 + c]; Mi[r] = (double)v_im[d*1024 + r*32 + c]; }
        else       { Mr[r] = (c - 32 == r) ? 1.0 : 0.0;       Mi[r] = 0.0; }
    }
#pragma unroll
    for (int col = 0; col < 32; ++col){
        double pr = __shfl(Mr[col], col, 64);
        double pi = __shfl(Mi[col], col, 64);
        double dm = pr*pr + pi*pi;
        double ir = pr/dm, ii = -pi/dm;
        double nr = Mr[col]*ir - Mi[col]*ii;
        double ni = Mr[col]*ii + Mi[col]*ir;
        Mr[col] = nr; Mi[col] = ni;
#pragma unroll
        for (int r = 0; r < 32; ++r){
            if (r == col) continue;
            double fr = __shfl(Mr[r], col, 64);
            double fi = __shfl(Mi[r], col, 64);
            Mr[r] -= fr*nr - fi*ni;
            Mi[r] -= fr*ni + fi*nr;
        }
    }
    if (c >= 32){
#pragma unroll
        for (int r = 0; r < 32; ++r)
            vinv[d*1024 + r*32 + (c - 32)] = make_float2((float)Mr[r], (float)Mi[r]);
    }
}

// ---------------- fp16 MFMA GEMM, 128x128 tile, global_load_lds staging ----------------
// C[M,N] = A[M,K] * B[N,K]^T. 4 waves, each 64x64 via 4x4 of 16x16x32 mfma.
// mode 0: f32 out = acc + bias[col]
// mode 1: f32 split-K partial at C + blockIdx.z*partStride
// mode 2: f16 out = silu(acc + bias[col])
__global__ __launch_bounds__(256) void k_gemm128(
    const f16* __restrict__ A, const f16* __restrict__ Bw,
    void* __restrict__ C, const float* __restrict__ bias,
    int N, int K, int klen, int partStride, int mode)
{
    __shared__ __align__(16) f16 As[128*32];
    __shared__ __align__(16) f16 Bs[128*32];
    const int tid = threadIdx.x;
    const int m0 = blockIdx.y * 128;
    const int n0 = blockIdx.x * 128;
    const int kbeg = blockIdx.z * klen;
    const int l = tid & 63;
    const int w = tid >> 6;
    const int fr = l & 15;
    const int fq = l >> 4;
    const int wm = (w >> 1) * 64;
    const int wn = (w & 1) * 64;
    // staging: issue i covers rows 64i..64i+63; lane layout = base + tid*16B (row-major [row][32k])
    const f16* gA = A  + (size_t)(m0 + (tid >> 2)) * K + kbeg + (tid & 3) * 8;
    const f16* gB = Bw + (size_t)(n0 + (tid >> 2)) * K + kbeg + (tid & 3) * 8;
    const size_t rowskip = (size_t)64 * K;
    f16* lA = As + tid * 8;
    f16* lB = Bs + tid * 8;
    f32x4 acc[4][4];
#pragma unroll
    for (int i = 0; i < 4; ++i)
#pragma unroll
        for (int j = 0; j < 4; ++j)
            acc[i][j] = (f32x4){0.f, 0.f, 0.f, 0.f};
    for (int kk = 0; kk < klen; kk += 32){
        __syncthreads();                 // previous chunk's LDS reads done
        gl_lds16(gA,           lA);
        gl_lds16(gA + rowskip, lA + 2048);
        gl_lds16(gB,           lB);
        gl_lds16(gB + rowskip, lB + 2048);
        gA += 32; gB += 32;
        __syncthreads();                 // drains vmcnt before barrier
        f16x8 af[4], bf[4];
#pragma unroll
        for (int i = 0; i < 4; ++i){
            af[i] = *(const f16x8*)(As + (wm + 16*i + fr) * 32 + fq * 8);
            bf[i] = *(const f16x8*)(Bs + (wn + 16*i + fr) * 32 + fq * 8);
        }
#pragma unroll
        for (int i = 0; i < 4; ++i)
#pragma unroll
            for (int j = 0; j < 4; ++j)
                acc[i][j] = __builtin_amdgcn_mfma_f32_16x16x32_f16(af[i], bf[j], acc[i][j], 0, 0, 0);
    }
    if (mode == 1){
        float* Cf = (float*)C + (size_t)blockIdx.z * partStride;
#pragma unroll
        for (int i = 0; i < 4; ++i)
#pragma unroll
            for (int j = 0; j < 4; ++j)
#pragma unroll
                for (int r = 0; r < 4; ++r){
                    int row = m0 + wm + 16*i + fq*4 + r;
                    int col = n0 + wn + 16*j + fr;
                    Cf[(size_t)row * N + col] = acc[i][j][r];
                }
    } else if (mode == 0){
        float* Cf = (float*)C;
#pragma unroll
        for (int i = 0; i < 4; ++i)
#pragma unroll
            for (int j = 0; j < 4; ++j)
#pragma unroll
                for (int r = 0; r < 4; ++r){
                    int row = m0 + wm + 16*i + fq*4 + r;
                    int col = n0 + wn + 16*j + fr;
                    Cf[(size_t)row * N + col] = acc[i][j][r] + bias[col];
                }
    } else {
        f16* Ch = (f16*)C;
#pragma unroll
        for (int i = 0; i < 4; ++i)
#pragma unroll
            for (int j = 0; j < 4; ++j)
#pragma unroll
                for (int r = 0; r < 4; ++r){
                    int row = m0 + wm + 16*i + fq*4 + r;
                    int col = n0 + wn + 16*j + fr;
                    float v = acc[i][j][r] + bias[col];
                    Ch[(size_t)row * N + col] = (f16)(v / (1.f + __expf(-v)));
                }
    }
}

// ---------------- split-K reduce: out = bias + (res?) + sum_{z<8} part[z] ----------------
__global__ void k_reduce8(float* __restrict__ out, const float* __restrict__ part,
                          const float* __restrict__ bias, const float* __restrict__ res, int n){
    int i = blockIdx.x * 256 + threadIdx.x;
    if (i >= n) return;
    float v = bias[i & (DIMC - 1)];
    if (res) v += res[i];
    float s = 0.f;
#pragma unroll
    for (int z = 0; z < 8; ++z) s += part[(size_t)z * n + i];
    out[i] = v + s;
}

// ---------------- split-K reduce + final LayerNorm -> fp16 (one row/block) ----------------
__global__ __launch_bounds__(128) void k_red8_ln(
    const float* __restrict__ part, const float* __restrict__ bias,
    const float* __restrict__ res, const float* __restrict__ g,
    const float* __restrict__ b, f16* __restrict__ out, int n)
{
    int row = blockIdx.x;
    int tid = threadIdx.x;
    __shared__ float sw[2], qw[2];
    float v[4]; float s = 0.f, q = 0.f;
#pragma unroll
    for (int j = 0; j < 4; ++j){
        int c = tid + 128*j;
        int idx = row*DIMC + c;
        float t = bias[c] + res[idx];
#pragma unroll
        for (int z = 0; z < 8; ++z) t += part[(size_t)z * n + idx];
        v[j] = t; s += t; q += t*t;
    }
    for (int off = 32; off; off >>= 1){ s += __shfl_down(s, off, 64); q += __shfl_down(q, off, 64); }
    if ((tid & 63) == 0){ sw[tid >> 6] = s; qw[tid >> 6] = q; }
    __syncthreads();
    float S = sw[0] + sw[1], Q = qw[0] + qw[1];
    float m = S / DIMC;
    float rstd = rsqrtf(Q / DIMC - m*m + 1e-5f);
#pragma unroll
    for (int j = 0; j < 4; ++j){
        int c = tid + 128*j;
        out[(size_t)row*DIMC + c] = (f16)((v[j] - m)*rstd*g[c] + b[c]);
    }
}

// ---------------- fused LN1 + gate projections + gate nonlinearity ----------------
__global__ __launch_bounds__(128) void k_siogate(
    const float* __restrict__ H, const float* __restrict__ g, const float* __restrict__ b,
    const float* __restrict__ wa, const float* __restrict__ wx,
    float2* __restrict__ a_t, float2* __restrict__ xc)
{
    __shared__ float zs[4][DIMC];
    __shared__ float sc[4][128];
    __shared__ float rs2[2], rq2[2];
    int tid = threadIdx.x;
    int r0 = blockIdx.x * 4;
    for (int gg = 0; gg < 4; ++gg){
        const float* xr = H + (size_t)(r0 + gg) * DIMC;
        float v[4]; float s = 0.f, q = 0.f;
#pragma unroll
        for (int j = 0; j < 4; ++j){ v[j] = xr[tid + 128*j]; s += v[j]; q += v[j]*v[j]; }
        for (int off = 32; off; off >>= 1){ s += __shfl_down(s, off, 64); q += __shfl_down(q, off, 64); }
        if ((tid & 63) == 0){ rs2[tid >> 6] = s; rq2[tid >> 6] = q; }
        __syncthreads();
        float m = (rs2[0] + rs2[1]) / DIMC;
        float var = (rq2[0] + rq2[1]) / DIMC - m*m;
        float rst = rsqrtf(var + 1e-5f);
#pragma unroll
        for (int j = 0; j < 4; ++j){ int c = tid + 128*j; zs[gg][c] = (v[j] - m)*rst*g[c] + b[c]; }
        __syncthreads();
    }
    const float* wrow = (tid < 64) ? (wa + (size_t)tid * DIMC) : (wx + (size_t)(tid - 64) * DIMC);
    float dot[4] = {0.f, 0.f, 0.f, 0.f};
    for (int c = 0; c < DIMC; c += 4){
        float4 wv = *(const float4*)(wrow + c);
#pragma unroll
        for (int gg = 0; gg < 4; ++gg){
            float4 zv = *(const float4*)(&zs[gg][c]);
            dot[gg] += wv.x*zv.x + wv.y*zv.y + wv.z*zv.z + wv.w*zv.w;
        }
    }
#pragma unroll
    for (int gg = 0; gg < 4; ++gg) sc[gg][tid] = dot[gg];
    __syncthreads();
    int gg = tid >> 5, k = tid & 31;
    int row = r0 + gg;
    int bb = row >> 9, t = row & 511;
    float re = sc[gg][2*k], im = sc[gg][2*k + 1];
    float m2 = re*re + im*im;
    float sa = rsqrtf(m2) * (m2 / (1.f + m2));
    a_t[(size_t)(bb*INNERC + k)*LC + t] = make_float2(re*sa, im*sa);
    float xr2 = sc[gg][64 + 2*k], xi2 = sc[gg][64 + 2*k + 1];
    float mx = xr2*xr2 + xi2*xi2;
    float sx = sqrtf(mx);
    xc[(size_t)row*INNERC + k] = make_float2(xr2*sx, xi2*sx);
}

// ---------------- w'[b,k,t] = sum_o Vinv[k,o] * x_roll[b,o,t] ----------------
__global__ __launch_bounds__(256) void k_wprime(
    const float2* __restrict__ xc, const float2* __restrict__ vinv,
    const float* __restrict__ h0re, const float* __restrict__ h0im,
    float2* __restrict__ w_t)
{
    int tid = threadIdx.x;
    int grp = tid >> 5, k = tid & 31;
    int bt = blockIdx.x * 8 + grp;
    int bb = bt >> 9, t = bt & 511;
    __shared__ float2 xr[8][32];
    if (t == 0) xr[grp][k] = make_float2(h0re[k], h0im[k]);
    else        xr[grp][k] = xc[(size_t)(bt - 1)*INNERC + k];
    __syncthreads();
    const float2* vr = vinv + k * INNERC;
    float2 acc = make_float2(0.f, 0.f);
#pragma unroll
    for (int o = 0; o < 32; ++o){
        float2 vv = vr[o], xx = xr[grp][o];
        acc.x += vv.x*xx.x - vv.y*xx.y;
        acc.y += vv.x*xx.y + vv.y*xx.x;
    }
    w_t[(size_t)(bb*INNERC + k)*LC + t] = acc;
}

// ---------------- scan e[t] = a[t]*(e[t-1] + w'[t]) ----------------
__global__ __launch_bounds__(64) void k_scan(
    const float2* __restrict__ a_t, const float2* __restrict__ w_t,
    float2* __restrict__ e)
{
    int bk = blockIdx.x;
    int l = threadIdx.x;
    int base = bk * LC + l * 8;
    float2 av[8], wv[8];
#pragma unroll
    for (int j = 0; j < 8; ++j){ av[j] = a_t[base + j]; wv[j] = w_t[base + j]; }
    float2 A = make_float2(1.f, 0.f), Bc = make_float2(0.f, 0.f);
#pragma unroll
    for (int j = 0; j < 8; ++j){
        Bc = cmul2(av[j], cadd2(Bc, wv[j]));
        A  = cmul2(av[j], A);
    }
    for (int off = 1; off < 64; off <<= 1){
        float Apx = __shfl_up(A.x,  off, 64), Apy = __shfl_up(A.y,  off, 64);
        float Bpx = __shfl_up(Bc.x, off, 64), Bpy = __shfl_up(Bc.y, off, 64);
        if (l >= off){
            float2 Ap = make_float2(Apx, Apy), Bp = make_float2(Bpx, Bpy);
            Bc = cadd2(cmul2(A, Bp), Bc);
            A  = cmul2(A, Ap);
        }
    }
    float ex = __shfl_up(Bc.x, 1, 64), ey = __shfl_up(Bc.y, 1, 64);
    float2 ecur = (l == 0) ? make_float2(0.f, 0.f) : make_float2(ex, ey);
    int bb = bk >> 5, k = bk & 31;
    size_t obase = ((size_t)bb*LC + l*8) * INNERC + k;
#pragma unroll
    for (int j = 0; j < 8; ++j){
        ecur = cmul2(av[j], cadd2(ecur, wv[j]));
        e[obase + (size_t)j * INNERC] = ecur;
    }
}

// ---------------- hr = Re(V*e)+Re(xc); val = hr@w_ol^T + res; hout=val; zout=LN2(val) f16 ----------------
__global__ __launch_bounds__(128) void k_siout_ln(
    const float2* __restrict__ e, const float2* __restrict__ xc,
    const float* __restrict__ vre, const float* __restrict__ vim,
    const float* __restrict__ wol, const float* __restrict__ res,
    const float* __restrict__ g2, const float* __restrict__ b2,
    float* __restrict__ hout, f16* __restrict__ zout)
{
    int bt = blockIdx.x;
    int tid = threadIdx.x;
    __shared__ float hr[INNERC];
    __shared__ float2 er[INNERC];
    __shared__ float sw[2], qw[2];
    if (tid < 32) er[tid] = e[(size_t)bt*INNERC + tid];
    __syncthreads();
    if (tid < 32){
        const float* vrr = vre + tid*INNERC;
        const float* vir = vim + tid*INNERC;
        float acc = xc[(size_t)bt*INNERC + tid].x;
#pragma unroll
        for (int k2 = 0; k2 < 32; ++k2) acc += vrr[k2]*er[k2].x - vir[k2]*er[k2].y;
        hr[tid] = acc;
    }
    __syncthreads();
    float v[4]; float s = 0.f, q = 0.f;
#pragma unroll
    for (int j = 0; j < 4; ++j){
        int n = tid + 128*j;
        float val = res[(size_t)bt*DIMC + n];
        const float* wr = wol + (size_t)n * INNERC;
#pragma unroll
        for (int i = 0; i < 32; ++i) val += hr[i]*wr[i];
        hout[(size_t)bt*DIMC + n] = val;
        v[j] = val; s += val; q += val*val;
    }
    for (int off = 32; off; off >>= 1){ s += __shfl_down(s, off, 64); q += __shfl_down(q, off, 64); }
    if ((tid & 63) == 0){ sw[tid >> 6] = s; qw[tid >> 6] = q; }
    __syncthreads();
    float S = sw[0] + sw[1], Q = qw[0] + qw[1];
    float m = S / DIMC;
    float rstd = rsqrtf(Q / DIMC - m*m + 1e-5f);
#pragma unroll
    for (int j = 0; j < 4; ++j){
        int n = tid + 128*j;
        zout[(size_t)bt*DIMC + n] = (f16)((v[j] - m)*rstd*g2[n] + b2[n]);
    }
}

extern "C" void kernel_launch(void* const* d_in, const int* in_sizes, int n_in,
                              void* d_out, int out_size, void* d_ws, size_t ws_size,
                              hipStream_t stream)
{
    const float* x     = (const float*)d_in[0];
    const float* w_in  = (const float*)d_in[1];
    const float* b_in  = (const float*)d_in[2];
    const float* ln1_g = (const float*)d_in[3];
    const float* ln1_b = (const float*)d_in[4];
    const float* wa    = (const float*)d_in[5];
    const float* wx    = (const float*)d_in[6];
    const float* v_re  = (const float*)d_in[7];
    const float* v_im  = (const float*)d_in[8];
    const float* h0_re = (const float*)d_in[9];
    const float* h0_im = (const float*)d_in[10];
    const float* w_ol  = (const float*)d_in[11];
    const float* ln2_g = (const float*)d_in[12];
    const float* ln2_b = (const float*)d_in[13];
    const float* w1    = (const float*)d_in[14];
    const float* b1    = (const float*)d_in[15];
    const float* w2    = (const float*)d_in[16];
    const float* b2    = (const float*)d_in[17];
    const float* lnl_g = (const float*)d_in[18];
    const float* lnl_b = (const float*)d_in[19];
    const float* w_out = (const float*)d_in[20];
    const float* b_out = (const float*)d_in[21];

    char* p = (char*)d_ws;
    f16* xb   = (f16*)p;   p += (size_t)NTOK * VOCABC * 2;
    f16* wib  = (f16*)p;   p += (size_t)DIMC * VOCABC * 2;
    f16* wob  = (f16*)p;   p += (size_t)VOCABC * DIMC * 2;
    f16* w1b  = (f16*)p;   p += (size_t)DEPTHC * FFC * DIMC * 2;
    f16* w2b  = (f16*)p;   p += (size_t)DEPTHC * DIMC * FFC * 2;
    float* h1 = (float*)p; p += (size_t)NTOK * DIMC * 4;
    float* h2 = (float*)p; p += (size_t)NTOK * DIMC * 4;
    float* h3 = (float*)p; p += (size_t)NTOK * DIMC * 4;
    f16* zb   = (f16*)p;   p += (size_t)NTOK * DIMC * 2;
    f16* ffb  = (f16*)p;   p += (size_t)NTOK * FFC * 2;
    float* pbuf = (float*)p; p += (size_t)8 * NTOK * DIMC * 4;
    float2* a_t = (float2*)p; p += (size_t)BC * INNERC * LC * 8;
    float2* w_t = (float2*)p; p += (size_t)BC * INNERC * LC * 8;
    float2* xc  = (float2*)p; p += (size_t)NTOK * INNERC * 8;
    float2* ev  = (float2*)p; p += (size_t)NTOK * INNERC * 8;
    float2* vinv = (float2*)p; p += (size_t)DEPTHC * INNERC * INNERC * 8;

    // fp32->fp16 converts in one dispatch (x, w_in, w1, w2, w_out)
    {
        dim3 g(NTOK * VOCABC / 1024, 5);
        k_f2h5<<<g, 256, 0, stream>>>(x, w_in, w1, w2, w_out,
                                      xb, wib, w1b, w2b, wob,
                                      NTOK*VOCABC, DIMC*VOCABC,
                                      DEPTHC*FFC*DIMC, DEPTHC*DIMC*FFC, VOCABC*DIMC);
    }
    k_inv<<<DEPTHC, 64, 0, stream>>>(v_re, v_im, vinv);

    // h1 = x @ w_in^T + b_in  (split-K=8, klen=1024)
    {
        dim3 g(DIMC/128, NTOK/128, 8);
        k_gemm128<<<g, 256, 0, stream>>>(xb, wib, pbuf, nullptr, DIMC, VOCABC, VOCABC/8, NTOK*DIMC, 1);
    }
    k_reduce8<<<(NTOK*DIMC)/256, 256, 0, stream>>>(h1, pbuf, b_in, nullptr, NTOK*DIMC);

    float* cur = h1;
    for (int d = 0; d < DEPTHC; ++d){
        float* hb = (d == 0) ? h2 : h3;   // post-sioconv residual
        k_siogate<<<NTOK/4, 128, 0, stream>>>(cur, ln1_g + d*DIMC, ln1_b + d*DIMC,
                                              wa + (size_t)d*2*INNERC*DIMC,
                                              wx + (size_t)d*2*INNERC*DIMC, a_t, xc);
        k_wprime<<<NTOK/8, 256, 0, stream>>>(xc, vinv + d*INNERC*INNERC,
                                             h0_re + d*INNERC, h0_im + d*INNERC, w_t);
        k_scan<<<BC*INNERC, 64, 0, stream>>>(a_t, w_t, ev);
        k_siout_ln<<<NTOK, 128, 0, stream>>>(ev, xc, v_re + d*INNERC*INNERC, v_im + d*INNERC*INNERC,
                                             w_ol + (size_t)d*DIMC*INNERC, cur,
                                             ln2_g + d*DIMC, ln2_b + d*DIMC, hb, zb);
        // FFN1: silu fused into epilogue, f16 out
        {
            dim3 g(FFC/128, NTOK/128, 1);
            k_gemm128<<<g, 256, 0, stream>>>(zb, w1b + (size_t)d*FFC*DIMC, ffb, b1 + d*FFC,
                                             FFC, DIMC, DIMC, 0, 2);
        }
        // FFN2: split-K=8, klen=256
        {
            dim3 g(DIMC/128, NTOK/128, 8);
            k_gemm128<<<g, 256, 0, stream>>>(ffb, w2b + (size_t)d*DIMC*FFC, pbuf, nullptr,
                                             DIMC, FFC, FFC/8, NTOK*DIMC, 1);
        }
        if (d == DEPTHC - 1){
            // reduce + residual + final LN -> zb (f16)
            k_red8_ln<<<NTOK, 128, 0, stream>>>(pbuf, b2 + d*DIMC, hb, lnl_g, lnl_b, zb, NTOK*DIMC);
        } else {
            float* hc = h1;  // next layer input (h1 free after siogate/siout of d=0? no: cur==h1 used as res above)
            hc = (d == 0) ? h3 : h1;
            k_reduce8<<<(NTOK*DIMC)/256, 256, 0, stream>>>(hc, pbuf, b2 + d*DIMC, hb, NTOK*DIMC);
            cur = hc;
        }
    }
    // out = zb @ w_out^T + b_out
    {
        dim3 g(VOCABC/128, NTOK/128, 1);
        k_gemm128<<<g, 256, 0, stream>>>(zb, wob, (float*)d_out, b_out, VOCABC, DIMC, DIMC, 0, 0);
    }
    (void)in_sizes; (void)n_in; (void)out_size; (void)ws_size;
}

// Round 3
// 414.365 us; speedup vs baseline: 1.2905x; 1.2905x over previous
//
#include <hip/hip_runtime.h>
#include <stdint.h>

#define DEPTHC 2
#define DIMC   512
#define FFC    2048
#define INNERC 32
#define VOCABC 8192
#define BC     2
#define LC     512
#define NTOK   1024   // B*L

typedef _Float16 f16;
typedef __attribute__((ext_vector_type(8))) _Float16 f16x8;
typedef __attribute__((ext_vector_type(4))) float f32x4;

__device__ __forceinline__ float2 cmul2(float2 a, float2 b){
    return make_float2(a.x*b.x - a.y*b.y, a.x*b.y + a.y*b.x);
}
__device__ __forceinline__ float2 cadd2(float2 a, float2 b){
    return make_float2(a.x + b.x, a.y + b.y);
}

__device__ __forceinline__ void gl_lds16(const void* g, void* l){
    __builtin_amdgcn_global_load_lds(
        (const __attribute__((address_space(1))) unsigned int*)g,
        (__attribute__((address_space(3))) unsigned int*)l, 16, 0, 0);
}

// ---------------- fused fp32 -> fp16 convert, flat-indexed over 5 tensors ----------------
__global__ void k_f2h5(const float* __restrict__ s0, const float* __restrict__ s1,
                       const float* __restrict__ s2, const float* __restrict__ s3,
                       const float* __restrict__ s4,
                       f16* __restrict__ d0, f16* __restrict__ d1, f16* __restrict__ d2,
                       f16* __restrict__ d3, f16* __restrict__ d4,
                       int n0, int n1, int n2, int n3, int n4){
    long long i = ((long long)blockIdx.x * 256 + threadIdx.x) * 4;
    const float* s; f16* d;
    if (i < n0){ s = s0; d = d0; }
    else { i -= n0;
        if (i < n1){ s = s1; d = d1; }
        else { i -= n1;
            if (i < n2){ s = s2; d = d2; }
            else { i -= n2;
                if (i < n3){ s = s3; d = d3; }
                else { i -= n3; if (i >= n4) return; s = s4; d = d4; }
            }
        }
    }
    float4 v = *(const float4*)(s + i);
    union { f16 h[4]; float2 f2; } u;
    u.h[0] = (f16)v.x; u.h[1] = (f16)v.y; u.h[2] = (f16)v.z; u.h[3] = (f16)v.w;
    *(float2*)(d + i) = u.f2;
}

// ---------------- complex 32x32 inverse: fp32 LDS Gauss-Jordan, 2 waves/matrix ----------------
// M stored as float2[row][64] (cols 0..31 matrix, 32..63 identity). Lane c owns column c;
// wave w owns rows 16w..16w+15. All LDS ops are b64, conflict-free; f-reads are broadcasts.
// Also packs h0 (re,im) into float2 for the scan kernel.
__global__ __launch_bounds__(128) void k_inv(const float* __restrict__ v_re,
                                             const float* __restrict__ v_im,
                                             const float* __restrict__ h0re,
                                             const float* __restrict__ h0im,
                                             float2* __restrict__ vinv,
                                             float2* __restrict__ h0c){
    int d = blockIdx.x;
    __shared__ float2 M[32][64];
    int tid = threadIdx.x;       // 128
    int c = tid & 63;
    int wv = tid >> 6;           // wave: rows 16wv..16wv+15
    if (tid < 32) h0c[d*32 + tid] = make_float2(h0re[d*32 + tid], h0im[d*32 + tid]);
#pragma unroll
    for (int rr = 0; rr < 16; ++rr){
        int r = wv*16 + rr;
        float re, im;
        if (c < 32){ re = v_re[d*1024 + r*32 + c]; im = v_im[d*1024 + r*32 + c]; }
        else       { re = (c - 32 == r) ? 1.f : 0.f; im = 0.f; }
        M[r][c] = make_float2(re, im);
    }
    __syncthreads();
    for (int col = 0; col < 32; ++col){
        float2 pv = M[col][col];                 // broadcast read
        float dm = pv.x*pv.x + pv.y*pv.y;
        float ir = pv.x/dm, ii = -pv.y/dm;
        if ((col >> 4) == wv){                   // owning wave scales pivot row
            float2 m0 = M[col][c];
            M[col][c] = make_float2(m0.x*ir - m0.y*ii, m0.x*ii + m0.y*ir);
        }
        __syncthreads();
        float2 nv = M[col][c];                   // scaled pivot-row value for own column
#pragma unroll
        for (int rr = 0; rr < 16; ++rr){
            int r = wv*16 + rr;
            if (r == col) continue;              // wave-uniform branch
            float2 f = M[r][col];                // broadcast read
            float2 m0 = M[r][c];
            m0.x -= f.x*nv.x - f.y*nv.y;
            m0.y -= f.x*nv.y + f.y*nv.x;
            M[r][c] = m0;
        }
        __syncthreads();
    }
    if (c >= 32){
#pragma unroll
        for (int rr = 0; rr < 16; ++rr){
            int r = wv*16 + rr;
            vinv[d*1024 + r*32 + (c - 32)] = M[r][c];
        }
    }
}

// ---------------- fp16 MFMA GEMM, MTxNT tile, global_load_lds staging ----------------
// C[M,N] = A[M,K] * B[N,K]^T. 4 waves in 2x2; wave tile (MT/2)x(NT/2).
// MODE 0: f32 out = acc + bias[col]; MODE 1: f32 split-K partial; MODE 2: f16 silu(acc+bias)
template<int MT, int NT, int MODE>
__global__ __launch_bounds__(256) void k_gemmT(
    const f16* __restrict__ A, const f16* __restrict__ Bw,
    void* __restrict__ C, const float* __restrict__ bias,
    int N, int K, int klen, int partStride)
{
    constexpr int RM = MT/32, RN = NT/32;
    __shared__ __align__(16) f16 As[MT*32];
    __shared__ __align__(16) f16 Bs[NT*32];
    const int tid = threadIdx.x;
    const int m0 = blockIdx.y * MT;
    const int n0 = blockIdx.x * NT;
    const int kbeg = blockIdx.z * klen;
    const int l = tid & 63;
    const int w = tid >> 6;
    const int fr = l & 15;
    const int fq = l >> 4;
    const int wm = (w >> 1) * (MT/2);
    const int wn = (w & 1) * (NT/2);
    const f16* gA = A  + (size_t)(m0 + (tid >> 2)) * K + kbeg + (tid & 3) * 8;
    const f16* gB = Bw + (size_t)(n0 + (tid >> 2)) * K + kbeg + (tid & 3) * 8;
    const size_t rowskip = (size_t)64 * K;
    f16* lA = As + tid * 8;
    f16* lB = Bs + tid * 8;
    f32x4 acc[RM][RN];
#pragma unroll
    for (int i = 0; i < RM; ++i)
#pragma unroll
        for (int j = 0; j < RN; ++j)
            acc[i][j] = (f32x4){0.f, 0.f, 0.f, 0.f};
    for (int kk = 0; kk < klen; kk += 32){
        __syncthreads();
#pragma unroll
        for (int i = 0; i < MT/64; ++i) gl_lds16(gA + i*rowskip, lA + i*2048);
#pragma unroll
        for (int i = 0; i < NT/64; ++i) gl_lds16(gB + i*rowskip, lB + i*2048);
        gA += 32; gB += 32;
        __syncthreads();
        f16x8 af[RM], bf[RN];
#pragma unroll
        for (int i = 0; i < RM; ++i) af[i] = *(const f16x8*)(As + (wm + 16*i + fr) * 32 + fq * 8);
#pragma unroll
        for (int j = 0; j < RN; ++j) bf[j] = *(const f16x8*)(Bs + (wn + 16*j + fr) * 32 + fq * 8);
#pragma unroll
        for (int i = 0; i < RM; ++i)
#pragma unroll
            for (int j = 0; j < RN; ++j)
                acc[i][j] = __builtin_amdgcn_mfma_f32_16x16x32_f16(af[i], bf[j], acc[i][j], 0, 0, 0);
    }
#pragma unroll
    for (int i = 0; i < RM; ++i)
#pragma unroll
        for (int j = 0; j < RN; ++j)
#pragma unroll
            for (int r = 0; r < 4; ++r){
                int row = m0 + wm + 16*i + fq*4 + r;
                int col = n0 + wn + 16*j + fr;
                if (MODE == 1){
                    ((float*)C + (size_t)blockIdx.z * partStride)[(size_t)row * N + col] = acc[i][j][r];
                } else if (MODE == 0){
                    ((float*)C)[(size_t)row * N + col] = acc[i][j][r] + bias[col];
                } else {
                    float v = acc[i][j][r] + bias[col];
                    ((f16*)C)[(size_t)row * N + col] = (f16)(v / (1.f + __expf(-v)));
                }
            }
}

// ---------------- split-K reduce: out = bias + (res?) + sum_{z<8} part[z] ----------------
__global__ void k_reduce8(float* __restrict__ out, const float* __restrict__ part,
                          const float* __restrict__ bias, const float* __restrict__ res, int n){
    int i = blockIdx.x * 256 + threadIdx.x;
    if (i >= n) return;
    float v = bias[i & (DIMC - 1)];
    if (res) v += res[i];
    float s = 0.f;
#pragma unroll
    for (int z = 0; z < 8; ++z) s += part[(size_t)z * n + i];
    out[i] = v + s;
}

// ---------------- split-K reduce + final LayerNorm -> fp16 (one row/block) ----------------
__global__ __launch_bounds__(128) void k_red8_ln(
    const float* __restrict__ part, const float* __restrict__ bias,
    const float* __restrict__ res, const float* __restrict__ g,
    const float* __restrict__ b, f16* __restrict__ out, int n)
{
    int row = blockIdx.x;
    int tid = threadIdx.x;
    __shared__ float sw[2], qw[2];
    float v[4]; float s = 0.f, q = 0.f;
#pragma unroll
    for (int j = 0; j < 4; ++j){
        int c = tid + 128*j;
        int idx = row*DIMC + c;
        float t = bias[c] + res[idx];
#pragma unroll
        for (int z = 0; z < 8; ++z) t += part[(size_t)z * n + idx];
        v[j] = t; s += t; q += t*t;
    }
    for (int off = 32; off; off >>= 1){ s += __shfl_down(s, off, 64); q += __shfl_down(q, off, 64); }
    if ((tid & 63) == 0){ sw[tid >> 6] = s; qw[tid >> 6] = q; }
    __syncthreads();
    float S = sw[0] + sw[1], Q = qw[0] + qw[1];
    float m = S / DIMC;
    float rstd = rsqrtf(Q / DIMC - m*m + 1e-5f);
#pragma unroll
    for (int j = 0; j < 4; ++j){
        int c = tid + 128*j;
        out[(size_t)row*DIMC + c] = (f16)((v[j] - m)*rstd*g[c] + b[c]);
    }
}

// ---------------- fused LN1 + gate projections + gate nonlinearity ----------------
__global__ __launch_bounds__(128) void k_siogate(
    const float* __restrict__ H, const float* __restrict__ g, const float* __restrict__ b,
    const float* __restrict__ wa, const float* __restrict__ wx,
    float2* __restrict__ a_t, float2* __restrict__ xc)
{
    __shared__ float zs[4][DIMC];
    __shared__ float sc[4][128];
    __shared__ float rs2[2], rq2[2];
    int tid = threadIdx.x;
    int r0 = blockIdx.x * 4;
    for (int gg = 0; gg < 4; ++gg){
        const float* xr = H + (size_t)(r0 + gg) * DIMC;
        float v[4]; float s = 0.f, q = 0.f;
#pragma unroll
        for (int j = 0; j < 4; ++j){ v[j] = xr[tid + 128*j]; s += v[j]; q += v[j]*v[j]; }
        for (int off = 32; off; off >>= 1){ s += __shfl_down(s, off, 64); q += __shfl_down(q, off, 64); }
        if ((tid & 63) == 0){ rs2[tid >> 6] = s; rq2[tid >> 6] = q; }
        __syncthreads();
        float m = (rs2[0] + rs2[1]) / DIMC;
        float var = (rq2[0] + rq2[1]) / DIMC - m*m;
        float rst = rsqrtf(var + 1e-5f);
#pragma unroll
        for (int j = 0; j < 4; ++j){ int c = tid + 128*j; zs[gg][c] = (v[j] - m)*rst*g[c] + b[c]; }
        __syncthreads();
    }
    const float* wrow = (tid < 64) ? (wa + (size_t)tid * DIMC) : (wx + (size_t)(tid - 64) * DIMC);
    float dot[4] = {0.f, 0.f, 0.f, 0.f};
    for (int c = 0; c < DIMC; c += 4){
        float4 wv = *(const float4*)(wrow + c);
#pragma unroll
        for (int gg = 0; gg < 4; ++gg){
            float4 zv = *(const float4*)(&zs[gg][c]);
            dot[gg] += wv.x*zv.x + wv.y*zv.y + wv.z*zv.z + wv.w*zv.w;
        }
    }
#pragma unroll
    for (int gg = 0; gg < 4; ++gg) sc[gg][tid] = dot[gg];
    __syncthreads();
    int gg = tid >> 5, k = tid & 31;
    int row = r0 + gg;
    int bb = row >> 9, t = row & 511;
    float re = sc[gg][2*k], im = sc[gg][2*k + 1];
    float m2 = re*re + im*im;
    float sa = rsqrtf(m2) * (m2 / (1.f + m2));
    a_t[(size_t)(bb*INNERC + k)*LC + t] = make_float2(re*sa, im*sa);
    float xr2 = sc[gg][64 + 2*k], xi2 = sc[gg][64 + 2*k + 1];
    float mx = xr2*xr2 + xi2*xi2;
    float sx = sqrtf(mx);
    xc[(size_t)row*INNERC + k] = make_float2(xr2*sx, xi2*sx);
}

// ---------------- fused wprime + scan: e[t] = a[t]*(e[t-1] + Vinv@xroll[t]) ----------------
__global__ __launch_bounds__(64) void k_scan(
    const float2* __restrict__ a_t, const float2* __restrict__ xc,
    const float2* __restrict__ vinv, const float2* __restrict__ h0c,
    float2* __restrict__ e)
{
    int bk = blockIdx.x;   // b*32 + k
    int l = threadIdx.x;   // 0..63, each owns 8 consecutive t
    int bb = bk >> 5, k = bk & 31;
    float2 vrow[32];
#pragma unroll
    for (int o = 0; o < 32; ++o) vrow[o] = vinv[k*32 + o];
    int base = bk * LC + l * 8;
    float2 av[8], wv[8];
#pragma unroll
    for (int j = 0; j < 8; ++j) av[j] = a_t[base + j];
#pragma unroll
    for (int j = 0; j < 8; ++j){
        int t = l*8 + j;
        const float2* src = (t == 0) ? h0c : (xc + (size_t)(bb*LC + t - 1) * INNERC);
        float2 acc = make_float2(0.f, 0.f);
#pragma unroll
        for (int o = 0; o < 32; o += 2){
            float4 qq = *(const float4*)(src + o);
            acc.x += vrow[o].x*qq.x - vrow[o].y*qq.y;
            acc.y += vrow[o].x*qq.y + vrow[o].y*qq.x;
            acc.x += vrow[o+1].x*qq.z - vrow[o+1].y*qq.w;
            acc.y += vrow[o+1].x*qq.w + vrow[o+1].y*qq.z;
        }
        wv[j] = acc;
    }
    float2 A = make_float2(1.f, 0.f), Bc = make_float2(0.f, 0.f);
#pragma unroll
    for (int j = 0; j < 8; ++j){
        Bc = cmul2(av[j], cadd2(Bc, wv[j]));
        A  = cmul2(av[j], A);
    }
    for (int off = 1; off < 64; off <<= 1){
        float Apx = __shfl_up(A.x,  off, 64), Apy = __shfl_up(A.y,  off, 64);
        float Bpx = __shfl_up(Bc.x, off, 64), Bpy = __shfl_up(Bc.y, off, 64);
        if (l >= off){
            float2 Ap = make_float2(Apx, Apy), Bp = make_float2(Bpx, Bpy);
            Bc = cadd2(cmul2(A, Bp), Bc);
            A  = cmul2(A, Ap);
        }
    }
    float ex = __shfl_up(Bc.x, 1, 64), ey = __shfl_up(Bc.y, 1, 64);
    float2 ecur = (l == 0) ? make_float2(0.f, 0.f) : make_float2(ex, ey);
    size_t obase = ((size_t)bb*LC + l*8) * INNERC + k;
#pragma unroll
    for (int j = 0; j < 8; ++j){
        ecur = cmul2(av[j], cadd2(ecur, wv[j]));
        e[obase + (size_t)j * INNERC] = ecur;
    }
}

// ---------------- hr = Re(V*e)+Re(xc); val = hr@w_ol^T + res; hout=val; zout=LN2(val) f16 ----------------
__global__ __launch_bounds__(128) void k_siout_ln(
    const float2* __restrict__ e, const float2* __restrict__ xc,
    const float* __restrict__ vre, const float* __restrict__ vim,
    const float* __restrict__ wol, const float* __restrict__ res,
    const float* __restrict__ g2, const float* __restrict__ b2,
    float* __restrict__ hout, f16* __restrict__ zout)
{
    int bt = blockIdx.x;
    int tid = threadIdx.x;
    __shared__ float hr[INNERC];
    __shared__ float2 er[INNERC];
    __shared__ float sw[2], qw[2];
    if (tid < 32) er[tid] = e[(size_t)bt*INNERC + tid];
    __syncthreads();
    if (tid < 32){
        const float* vrr = vre + tid*INNERC;
        const float* vir = vim + tid*INNERC;
        float acc = xc[(size_t)bt*INNERC + tid].x;
#pragma unroll
        for (int k2 = 0; k2 < 32; ++k2) acc += vrr[k2]*er[k2].x - vir[k2]*er[k2].y;
        hr[tid] = acc;
    }
    __syncthreads();
    float v[4]; float s = 0.f, q = 0.f;
#pragma unroll
    for (int j = 0; j < 4; ++j){
        int n = tid + 128*j;
        float val = res[(size_t)bt*DIMC + n];
        const float* wr = wol + (size_t)n * INNERC;
#pragma unroll
        for (int i = 0; i < 32; ++i) val += hr[i]*wr[i];
        hout[(size_t)bt*DIMC + n] = val;
        v[j] = val; s += val; q += val*val;
    }
    for (int off = 32; off; off >>= 1){ s += __shfl_down(s, off, 64); q += __shfl_down(q, off, 64); }
    if ((tid & 63) == 0){ sw[tid >> 6] = s; qw[tid >> 6] = q; }
    __syncthreads();
    float S = sw[0] + sw[1], Q = qw[0] + qw[1];
    float m = S / DIMC;
    float rstd = rsqrtf(Q / DIMC - m*m + 1e-5f);
#pragma unroll
    for (int j = 0; j < 4; ++j){
        int n = tid + 128*j;
        zout[(size_t)bt*DIMC + n] = (f16)((v[j] - m)*rstd*g2[n] + b2[n]);
    }
}

extern "C" void kernel_launch(void* const* d_in, const int* in_sizes, int n_in,
                              void* d_out, int out_size, void* d_ws, size_t ws_size,
                              hipStream_t stream)
{
    const float* x     = (const float*)d_in[0];
    const float* w_in  = (const float*)d_in[1];
    const float* b_in  = (const float*)d_in[2];
    const float* ln1_g = (const float*)d_in[3];
    const float* ln1_b = (const float*)d_in[4];
    const float* wa    = (const float*)d_in[5];
    const float* wx    = (const float*)d_in[6];
    const float* v_re  = (const float*)d_in[7];
    const float* v_im  = (const float*)d_in[8];
    const float* h0_re = (const float*)d_in[9];
    const float* h0_im = (const float*)d_in[10];
    const float* w_ol  = (const float*)d_in[11];
    const float* ln2_g = (const float*)d_in[12];
    const float* ln2_b = (const float*)d_in[13];
    const float* w1    = (const float*)d_in[14];
    const float* b1    = (const float*)d_in[15];
    const float* w2    = (const float*)d_in[16];
    const float* b2    = (const float*)d_in[17];
    const float* lnl_g = (const float*)d_in[18];
    const float* lnl_b = (const float*)d_in[19];
    const float* w_out = (const float*)d_in[20];
    const float* b_out = (const float*)d_in[21];

    char* p = (char*)d_ws;
    f16* xb   = (f16*)p;   p += (size_t)NTOK * VOCABC * 2;
    f16* wib  = (f16*)p;   p += (size_t)DIMC * VOCABC * 2;
    f16* wob  = (f16*)p;   p += (size_t)VOCABC * DIMC * 2;
    f16* w1b  = (f16*)p;   p += (size_t)DEPTHC * FFC * DIMC * 2;
    f16* w2b  = (f16*)p;   p += (size_t)DEPTHC * DIMC * FFC * 2;
    float* h1 = (float*)p; p += (size_t)NTOK * DIMC * 4;
    float* h2 = (float*)p; p += (size_t)NTOK * DIMC * 4;
    float* h3 = (float*)p; p += (size_t)NTOK * DIMC * 4;
    f16* zb   = (f16*)p;   p += (size_t)NTOK * DIMC * 2;
    f16* ffb  = (f16*)p;   p += (size_t)NTOK * FFC * 2;
    float* pbuf = (float*)p; p += (size_t)8 * NTOK * DIMC * 4;
    float2* a_t = (float2*)p; p += (size_t)BC * INNERC * LC * 8;
    float2* xc  = (float2*)p; p += (size_t)NTOK * INNERC * 8;
    float2* ev  = (float2*)p; p += (size_t)NTOK * INNERC * 8;
    float2* vinv = (float2*)p; p += (size_t)DEPTHC * INNERC * INNERC * 8;
    float2* h0c  = (float2*)p; p += (size_t)DEPTHC * INNERC * 8;

    // fp32->fp16 converts, flat grid (x, w_in, w1, w2, w_out): 20.97M elems / 1024 per block
    {
        const int n0 = NTOK*VOCABC, n1 = DIMC*VOCABC, n2 = DEPTHC*FFC*DIMC,
                  n3 = DEPTHC*DIMC*FFC, n4 = VOCABC*DIMC;
        int blocks = (n0 + n1 + n2 + n3 + n4) / 1024;
        k_f2h5<<<blocks, 256, 0, stream>>>(x, w_in, w1, w2, w_out,
                                           xb, wib, w1b, w2b, wob, n0, n1, n2, n3, n4);
    }
    k_inv<<<DEPTHC, 128, 0, stream>>>(v_re, v_im, h0_re, h0_im, vinv, h0c);

    // h1 = x @ w_in^T + b_in  (64x128 tile, split-K=8)
    {
        dim3 g(DIMC/128, NTOK/64, 8);
        k_gemmT<64,128,1><<<g, 256, 0, stream>>>(xb, wib, pbuf, nullptr, DIMC, VOCABC, VOCABC/8, NTOK*DIMC);
    }
    k_reduce8<<<(NTOK*DIMC)/256, 256, 0, stream>>>(h1, pbuf, b_in, nullptr, NTOK*DIMC);

    float* cur = h1;
    for (int d = 0; d < DEPTHC; ++d){
        float* hb = (d == 0) ? h2 : h2;      // sio+residual out (h2 free again by d=1)
        float* hc = h3;                       // layer out (d=0 only)
        k_siogate<<<NTOK/4, 128, 0, stream>>>(cur, ln1_g + d*DIMC, ln1_b + d*DIMC,
                                              wa + (size_t)d*2*INNERC*DIMC,
                                              wx + (size_t)d*2*INNERC*DIMC, a_t, xc);
        k_scan<<<BC*INNERC, 64, 0, stream>>>(a_t, xc, vinv + d*INNERC*INNERC, h0c + d*INNERC, ev);
        k_siout_ln<<<NTOK, 128, 0, stream>>>(ev, xc, v_re + d*INNERC*INNERC, v_im + d*INNERC*INNERC,
                                             w_ol + (size_t)d*DIMC*INNERC, cur,
                                             ln2_g + d*DIMC, ln2_b + d*DIMC, hb, zb);
        // FFN1: 64x128 tile, silu fused, f16 out
        {
            dim3 g(FFC/128, NTOK/64, 1);
            k_gemmT<64,128,2><<<g, 256, 0, stream>>>(zb, w1b + (size_t)d*FFC*DIMC, ffb, b1 + d*FFC,
                                                     FFC, DIMC, DIMC, 0);
        }
        // FFN2: 64x128 tile, split-K=8
        {
            dim3 g(DIMC/128, NTOK/64, 8);
            k_gemmT<64,128,1><<<g, 256, 0, stream>>>(ffb, w2b + (size_t)d*DIMC*FFC, pbuf, nullptr,
                                                     DIMC, FFC, FFC/8, NTOK*DIMC);
        }
        if (d == DEPTHC - 1){
            k_red8_ln<<<NTOK, 128, 0, stream>>>(pbuf, b2 + d*DIMC, hb, lnl_g, lnl_b, zb, NTOK*DIMC);
        } else {
            k_reduce8<<<(NTOK*DIMC)/256, 256, 0, stream>>>(hc, pbuf, b2 + d*DIMC, hb, NTOK*DIMC);
            cur = hc;
        }
    }
    // out = zb @ w_out^T + b_out  (128x128 tile)
    {
        dim3 g(VOCABC/128, NTOK/128, 1);
        k_gemmT<128,128,0><<<g, 256, 0, stream>>>(zb, wob, (float*)d_out, b_out, VOCABC, DIMC, DIMC, 0);
    }
    (void)in_sizes; (void)n_in; (void)out_size; (void)ws_size;
}

// Round 4
// 385.194 us; speedup vs baseline: 1.3883x; 1.0757x over previous
//
#include <hip/hip_runtime.h>
#include <stdint.h>

#define DEPTHC 2
#define DIMC   512
#define FFC    2048
#define INNERC 32
#define VOCABC 8192
#define BC     2
#define LC     512
#define NTOK   1024   // B*L

typedef _Float16 f16;
typedef __attribute__((ext_vector_type(8))) _Float16 f16x8;
typedef __attribute__((ext_vector_type(4))) float f32x4;

__device__ __forceinline__ float2 cmul2(float2 a, float2 b){
    return make_float2(a.x*b.x - a.y*b.y, a.x*b.y + a.y*b.x);
}
__device__ __forceinline__ float2 cadd2(float2 a, float2 b){
    return make_float2(a.x + b.x, a.y + b.y);
}

__device__ __forceinline__ void gl_lds16(const void* g, void* l){
    __builtin_amdgcn_global_load_lds(
        (const __attribute__((address_space(1))) unsigned int*)g,
        (__attribute__((address_space(3))) unsigned int*)l, 16, 0, 0);
}

// ---------------- prep: blocks 0..1 = complex 32x32 inverse; blocks 2.. = fp32->fp16 convert ----
// Inverse: unnormalized Gauss-Jordan in LDS float2[32][64] (cols 0..31 matrix, 32..63 identity).
// Lane c owns column c; wave wv owns rows 8wv..8wv+7. No pivot-row write during elimination
// -> exactly ONE barrier per column, no cross-wave hazard. Epilogue divides row r by M[r][r].
// Runs concurrently with the HBM-bound convert blocks, so its latency is hidden.
__global__ __launch_bounds__(256) void k_prep(
    const float* __restrict__ s0, const float* __restrict__ s1,
    const float* __restrict__ s2, const float* __restrict__ s3,
    const float* __restrict__ s4,
    f16* __restrict__ d0, f16* __restrict__ d1, f16* __restrict__ d2,
    f16* __restrict__ d3, f16* __restrict__ d4,
    int n0, int n1, int n2, int n3, int n4,
    const float* __restrict__ v_re, const float* __restrict__ v_im,
    const float* __restrict__ h0re, const float* __restrict__ h0im,
    float2* __restrict__ vinv, float2* __restrict__ h0c)
{
    __shared__ float2 M[32][64];
    if (blockIdx.x < 2){
        const int d = blockIdx.x;
        const int tid = threadIdx.x;
        const int c = tid & 63;
        const int wv = tid >> 6;             // 4 waves, rows 8wv..8wv+7
        if (tid < 32) h0c[d*32 + tid] = make_float2(h0re[d*32 + tid], h0im[d*32 + tid]);
#pragma unroll
        for (int rr = 0; rr < 8; ++rr){
            int r = wv*8 + rr;
            float re, im;
            if (c < 32){ re = v_re[d*1024 + r*32 + c]; im = v_im[d*1024 + r*32 + c]; }
            else       { re = (c - 32 == r) ? 1.f : 0.f; im = 0.f; }
            M[r][c] = make_float2(re, im);
        }
        __syncthreads();
#pragma unroll 1
        for (int col = 0; col < 32; ++col){
            float2 prow = M[col][c];                 // pivot row, own column
            float pvx = __shfl(prow.x, col, 64);     // pivot value broadcast (in-regs)
            float pvy = __shfl(prow.y, col, 64);
            float dm = pvx*pvx + pvy*pvy;
            float ir = pvx/dm, ii = -pvy/dm;
            float2 nv = make_float2(prow.x*ir - prow.y*ii, prow.x*ii + prow.y*ir);
#pragma unroll
            for (int rr = 0; rr < 8; ++rr){
                int r = wv*8 + rr;
                if (r == col) continue;              // pivot row untouched (stays unnormalized)
                float2 f  = M[r][col];               // broadcast read
                float2 m0 = M[r][c];
                m0.x -= f.x*nv.x - f.y*nv.y;
                m0.y -= f.x*nv.y + f.y*nv.x;
                M[r][c] = m0;
            }
            __syncthreads();                          // one barrier per column
        }
        if (c >= 32){
#pragma unroll
            for (int rr = 0; rr < 8; ++rr){
                int r = wv*8 + rr;
                float2 dv = M[r][r];                  // final diagonal (pivot) value
                float dm = dv.x*dv.x + dv.y*dv.y;
                float ir = dv.x/dm, ii = -dv.y/dm;
                float2 m0 = M[r][c];
                vinv[d*1024 + r*32 + (c - 32)] =
                    make_float2(m0.x*ir - m0.y*ii, m0.x*ii + m0.y*ir);
            }
        }
        return;
    }
    long long i = ((long long)(blockIdx.x - 2) * 256 + threadIdx.x) * 4;
    const float* s; f16* d;
    if (i < n0){ s = s0; d = d0; }
    else { i -= n0;
        if (i < n1){ s = s1; d = d1; }
        else { i -= n1;
            if (i < n2){ s = s2; d = d2; }
            else { i -= n2;
                if (i < n3){ s = s3; d = d3; }
                else { i -= n3; if (i >= n4) return; s = s4; d = d4; }
            }
        }
    }
    float4 v = *(const float4*)(s + i);
    union { f16 h[4]; float2 f2; } u;
    u.h[0] = (f16)v.x; u.h[1] = (f16)v.y; u.h[2] = (f16)v.z; u.h[3] = (f16)v.w;
    *(float2*)(d + i) = u.f2;
}

// ---------------- fp16 MFMA GEMM, MTxNT tile, global_load_lds staging ----------------
// C[M,N] = A[M,K] * B[N,K]^T. 4 waves in 2x2; wave tile (MT/2)x(NT/2).
// MODE 0: f32 out = acc + bias[col]; MODE 1: f32 split-K partial; MODE 2: f16 silu(acc+bias)
template<int MT, int NT, int MODE>
__global__ __launch_bounds__(256) void k_gemmT(
    const f16* __restrict__ A, const f16* __restrict__ Bw,
    void* __restrict__ C, const float* __restrict__ bias,
    int N, int K, int klen, int partStride)
{
    constexpr int RM = MT/32, RN = NT/32;
    __shared__ __align__(16) f16 As[MT*32];
    __shared__ __align__(16) f16 Bs[NT*32];
    const int tid = threadIdx.x;
    const int m0 = blockIdx.y * MT;
    const int n0 = blockIdx.x * NT;
    const int kbeg = blockIdx.z * klen;
    const int l = tid & 63;
    const int w = tid >> 6;
    const int fr = l & 15;
    const int fq = l >> 4;
    const int wm = (w >> 1) * (MT/2);
    const int wn = (w & 1) * (NT/2);
    const f16* gA = A  + (size_t)(m0 + (tid >> 2)) * K + kbeg + (tid & 3) * 8;
    const f16* gB = Bw + (size_t)(n0 + (tid >> 2)) * K + kbeg + (tid & 3) * 8;
    const size_t rowskip = (size_t)64 * K;
    f16* lA = As + tid * 8;
    f16* lB = Bs + tid * 8;
    f32x4 acc[RM][RN];
#pragma unroll
    for (int i = 0; i < RM; ++i)
#pragma unroll
        for (int j = 0; j < RN; ++j)
            acc[i][j] = (f32x4){0.f, 0.f, 0.f, 0.f};
    for (int kk = 0; kk < klen; kk += 32){
        __syncthreads();
#pragma unroll
        for (int i = 0; i < MT/64; ++i) gl_lds16(gA + i*rowskip, lA + i*2048);
#pragma unroll
        for (int i = 0; i < NT/64; ++i) gl_lds16(gB + i*rowskip, lB + i*2048);
        gA += 32; gB += 32;
        __syncthreads();
        f16x8 af[RM], bf[RN];
#pragma unroll
        for (int i = 0; i < RM; ++i) af[i] = *(const f16x8*)(As + (wm + 16*i + fr) * 32 + fq * 8);
#pragma unroll
        for (int j = 0; j < RN; ++j) bf[j] = *(const f16x8*)(Bs + (wn + 16*j + fr) * 32 + fq * 8);
#pragma unroll
        for (int i = 0; i < RM; ++i)
#pragma unroll
            for (int j = 0; j < RN; ++j)
                acc[i][j] = __builtin_amdgcn_mfma_f32_16x16x32_f16(af[i], bf[j], acc[i][j], 0, 0, 0);
    }
#pragma unroll
    for (int i = 0; i < RM; ++i)
#pragma unroll
        for (int j = 0; j < RN; ++j)
#pragma unroll
            for (int r = 0; r < 4; ++r){
                int row = m0 + wm + 16*i + fq*4 + r;
                int col = n0 + wn + 16*j + fr;
                if (MODE == 1){
                    ((float*)C + (size_t)blockIdx.z * partStride)[(size_t)row * N + col] = acc[i][j][r];
                } else if (MODE == 0){
                    ((float*)C)[(size_t)row * N + col] = acc[i][j][r] + bias[col];
                } else {
                    float v = acc[i][j][r] + bias[col];
                    ((f16*)C)[(size_t)row * N + col] = (f16)(v / (1.f + __expf(-v)));
                }
            }
}

// ---------------- split-K reduce + final LayerNorm -> fp16 (one row/block) ----------------
__global__ __launch_bounds__(128) void k_red8_ln(
    const float* __restrict__ part, const float* __restrict__ bias,
    const float* __restrict__ res, const float* __restrict__ g,
    const float* __restrict__ b, f16* __restrict__ out, int n)
{
    int row = blockIdx.x;
    int tid = threadIdx.x;
    __shared__ float sw[2], qw[2];
    float v[4]; float s = 0.f, q = 0.f;
#pragma unroll
    for (int j = 0; j < 4; ++j){
        int c = tid + 128*j;
        int idx = row*DIMC + c;
        float t = bias[c] + res[idx];
#pragma unroll
        for (int z = 0; z < 8; ++z) t += part[(size_t)z * n + idx];
        v[j] = t; s += t; q += t*t;
    }
    for (int off = 32; off; off >>= 1){ s += __shfl_down(s, off, 64); q += __shfl_down(q, off, 64); }
    if ((tid & 63) == 0){ sw[tid >> 6] = s; qw[tid >> 6] = q; }
    __syncthreads();
    float S = sw[0] + sw[1], Q = qw[0] + qw[1];
    float m = S / DIMC;
    float rstd = rsqrtf(Q / DIMC - m*m + 1e-5f);
#pragma unroll
    for (int j = 0; j < 4; ++j){
        int c = tid + 128*j;
        out[(size_t)row*DIMC + c] = (f16)((v[j] - m)*rstd*g[c] + b[c]);
    }
}

// ---------------- fused split-K reduce + residual + LN1 + gate projections ----------------
// h[row] = bias + (res?) + sum_z part[z][row]; hout=h; z=LN1(h); gates from z@wa^T, z@wx^T.
__global__ __launch_bounds__(128) void k_siogate(
    const float* __restrict__ part, const float* __restrict__ bias,
    const float* __restrict__ res, float* __restrict__ hout,
    const float* __restrict__ g, const float* __restrict__ b,
    const float* __restrict__ wa, const float* __restrict__ wx,
    float2* __restrict__ a_t, float2* __restrict__ xc)
{
    __shared__ float zs[4][DIMC];
    __shared__ float sc[4][128];
    __shared__ float rs2[2], rq2[2];
    int tid = threadIdx.x;
    int r0 = blockIdx.x * 4;
    const int n = NTOK * DIMC;
    for (int gg = 0; gg < 4; ++gg){
        int row = r0 + gg;
        float v[4]; float s = 0.f, q = 0.f;
#pragma unroll
        for (int j = 0; j < 4; ++j){
            int c = tid + 128*j;
            int idx = row*DIMC + c;
            float t = bias[c];
            if (res) t += res[idx];
#pragma unroll
            for (int z = 0; z < 8; ++z) t += part[(size_t)z * n + idx];
            hout[idx] = t;
            v[j] = t; s += t; q += t*t;
        }
        for (int off = 32; off; off >>= 1){ s += __shfl_down(s, off, 64); q += __shfl_down(q, off, 64); }
        if ((tid & 63) == 0){ rs2[tid >> 6] = s; rq2[tid >> 6] = q; }
        __syncthreads();
        float m = (rs2[0] + rs2[1]) / DIMC;
        float var = (rq2[0] + rq2[1]) / DIMC - m*m;
        float rst = rsqrtf(var + 1e-5f);
#pragma unroll
        for (int j = 0; j < 4; ++j){ int c = tid + 128*j; zs[gg][c] = (v[j] - m)*rst*g[c] + b[c]; }
        __syncthreads();
    }
    const float* wrow = (tid < 64) ? (wa + (size_t)tid * DIMC) : (wx + (size_t)(tid - 64) * DIMC);
    float dot[4] = {0.f, 0.f, 0.f, 0.f};
    for (int c = 0; c < DIMC; c += 4){
        float4 wv = *(const float4*)(wrow + c);
#pragma unroll
        for (int gg = 0; gg < 4; ++gg){
            float4 zv = *(const float4*)(&zs[gg][c]);
            dot[gg] += wv.x*zv.x + wv.y*zv.y + wv.z*zv.z + wv.w*zv.w;
        }
    }
#pragma unroll
    for (int gg = 0; gg < 4; ++gg) sc[gg][tid] = dot[gg];
    __syncthreads();
    int gg = tid >> 5, k = tid & 31;
    int row = r0 + gg;
    int bb = row >> 9, t = row & 511;
    float re = sc[gg][2*k], im = sc[gg][2*k + 1];
    float m2 = re*re + im*im;
    float sa = rsqrtf(m2) * (m2 / (1.f + m2));
    a_t[(size_t)(bb*INNERC + k)*LC + t] = make_float2(re*sa, im*sa);
    float xr2 = sc[gg][64 + 2*k], xi2 = sc[gg][64 + 2*k + 1];
    float mx = xr2*xr2 + xi2*xi2;
    float sx = sqrtf(mx);
    xc[(size_t)row*INNERC + k] = make_float2(xr2*sx, xi2*sx);
}

// ---------------- fused wprime + scan: e[t] = a[t]*(e[t-1] + Vinv@xroll[t]) ----------------
__global__ __launch_bounds__(64) void k_scan(
    const float2* __restrict__ a_t, const float2* __restrict__ xc,
    const float2* __restrict__ vinv, const float2* __restrict__ h0c,
    float2* __restrict__ e)
{
    int bk = blockIdx.x;   // b*32 + k
    int l = threadIdx.x;   // 0..63, each owns 8 consecutive t
    int bb = bk >> 5, k = bk & 31;
    float2 vrow[32];
#pragma unroll
    for (int o = 0; o < 32; ++o) vrow[o] = vinv[k*32 + o];
    int base = bk * LC + l * 8;
    float2 av[8], wv[8];
#pragma unroll
    for (int j = 0; j < 8; ++j) av[j] = a_t[base + j];
#pragma unroll
    for (int j = 0; j < 8; ++j){
        int t = l*8 + j;
        const float2* src = (t == 0) ? h0c : (xc + (size_t)(bb*LC + t - 1) * INNERC);
        float2 acc = make_float2(0.f, 0.f);
#pragma unroll
        for (int o = 0; o < 32; o += 2){
            float4 qq = *(const float4*)(src + o);
            acc.x += vrow[o].x*qq.x - vrow[o].y*qq.y;
            acc.y += vrow[o].x*qq.y + vrow[o].y*qq.x;
            acc.x += vrow[o+1].x*qq.z - vrow[o+1].y*qq.w;
            acc.y += vrow[o+1].x*qq.w + vrow[o+1].y*qq.z;
        }
        wv[j] = acc;
    }
    float2 A = make_float2(1.f, 0.f), Bc = make_float2(0.f, 0.f);
#pragma unroll
    for (int j = 0; j < 8; ++j){
        Bc = cmul2(av[j], cadd2(Bc, wv[j]));
        A  = cmul2(av[j], A);
    }
    for (int off = 1; off < 64; off <<= 1){
        float Apx = __shfl_up(A.x,  off, 64), Apy = __shfl_up(A.y,  off, 64);
        float Bpx = __shfl_up(Bc.x, off, 64), Bpy = __shfl_up(Bc.y, off, 64);
        if (l >= off){
            float2 Ap = make_float2(Apx, Apy), Bp = make_float2(Bpx, Bpy);
            Bc = cadd2(cmul2(A, Bp), Bc);
            A  = cmul2(A, Ap);
        }
    }
    float ex = __shfl_up(Bc.x, 1, 64), ey = __shfl_up(Bc.y, 1, 64);
    float2 ecur = (l == 0) ? make_float2(0.f, 0.f) : make_float2(ex, ey);
    size_t obase = ((size_t)bb*LC + l*8) * INNERC + k;
#pragma unroll
    for (int j = 0; j < 8; ++j){
        ecur = cmul2(av[j], cadd2(ecur, wv[j]));
        e[obase + (size_t)j * INNERC] = ecur;
    }
}

// ---------------- hr = Re(V*e)+Re(xc); val = hr@w_ol^T + res; hout=val; zout=LN2(val) f16 ----------------
__global__ __launch_bounds__(128) void k_siout_ln(
    const float2* __restrict__ e, const float2* __restrict__ xc,
    const float* __restrict__ vre, const float* __restrict__ vim,
    const float* __restrict__ wol, const float* __restrict__ res,
    const float* __restrict__ g2, const float* __restrict__ b2,
    float* __restrict__ hout, f16* __restrict__ zout)
{
    int bt = blockIdx.x;
    int tid = threadIdx.x;
    __shared__ float hr[INNERC];
    __shared__ float2 er[INNERC];
    __shared__ float sw[2], qw[2];
    if (tid < 32) er[tid] = e[(size_t)bt*INNERC + tid];
    __syncthreads();
    if (tid < 32){
        const float* vrr = vre + tid*INNERC;
        const float* vir = vim + tid*INNERC;
        float acc = xc[(size_t)bt*INNERC + tid].x;
#pragma unroll
        for (int k2 = 0; k2 < 32; ++k2) acc += vrr[k2]*er[k2].x - vir[k2]*er[k2].y;
        hr[tid] = acc;
    }
    __syncthreads();
    float v[4]; float s = 0.f, q = 0.f;
#pragma unroll
    for (int j = 0; j < 4; ++j){
        int n = tid + 128*j;
        float val = res[(size_t)bt*DIMC + n];
        const float* wr = wol + (size_t)n * INNERC;
#pragma unroll
        for (int i = 0; i < 32; ++i) val += hr[i]*wr[i];
        hout[(size_t)bt*DIMC + n] = val;
        v[j] = val; s += val; q += val*val;
    }
    for (int off = 32; off; off >>= 1){ s += __shfl_down(s, off, 64); q += __shfl_down(q, off, 64); }
    if ((tid & 63) == 0){ sw[tid >> 6] = s; qw[tid >> 6] = q; }
    __syncthreads();
    float S = sw[0] + sw[1], Q = qw[0] + qw[1];
    float m = S / DIMC;
    float rstd = rsqrtf(Q / DIMC - m*m + 1e-5f);
#pragma unroll
    for (int j = 0; j < 4; ++j){
        int n = tid + 128*j;
        zout[(size_t)bt*DIMC + n] = (f16)((v[j] - m)*rstd*g2[n] + b2[n]);
    }
}

extern "C" void kernel_launch(void* const* d_in, const int* in_sizes, int n_in,
                              void* d_out, int out_size, void* d_ws, size_t ws_size,
                              hipStream_t stream)
{
    const float* x     = (const float*)d_in[0];
    const float* w_in  = (const float*)d_in[1];
    const float* b_in  = (const float*)d_in[2];
    const float* ln1_g = (const float*)d_in[3];
    const float* ln1_b = (const float*)d_in[4];
    const float* wa    = (const float*)d_in[5];
    const float* wx    = (const float*)d_in[6];
    const float* v_re  = (const float*)d_in[7];
    const float* v_im  = (const float*)d_in[8];
    const float* h0_re = (const float*)d_in[9];
    const float* h0_im = (const float*)d_in[10];
    const float* w_ol  = (const float*)d_in[11];
    const float* ln2_g = (const float*)d_in[12];
    const float* ln2_b = (const float*)d_in[13];
    const float* w1    = (const float*)d_in[14];
    const float* b1    = (const float*)d_in[15];
    const float* w2    = (const float*)d_in[16];
    const float* b2    = (const float*)d_in[17];
    const float* lnl_g = (const float*)d_in[18];
    const float* lnl_b = (const float*)d_in[19];
    const float* w_out = (const float*)d_in[20];
    const float* b_out = (const float*)d_in[21];

    char* p = (char*)d_ws;
    f16* xb   = (f16*)p;   p += (size_t)NTOK * VOCABC * 2;
    f16* wib  = (f16*)p;   p += (size_t)DIMC * VOCABC * 2;
    f16* wob  = (f16*)p;   p += (size_t)VOCABC * DIMC * 2;
    f16* w1b  = (f16*)p;   p += (size_t)DEPTHC * FFC * DIMC * 2;
    f16* w2b  = (f16*)p;   p += (size_t)DEPTHC * DIMC * FFC * 2;
    float* h1 = (float*)p; p += (size_t)NTOK * DIMC * 4;
    float* h2 = (float*)p; p += (size_t)NTOK * DIMC * 4;
    float* h3 = (float*)p; p += (size_t)NTOK * DIMC * 4;
    f16* zb   = (f16*)p;   p += (size_t)NTOK * DIMC * 2;
    f16* ffb  = (f16*)p;   p += (size_t)NTOK * FFC * 2;
    float* pbuf = (float*)p; p += (size_t)8 * NTOK * DIMC * 4;
    float2* a_t = (float2*)p; p += (size_t)BC * INNERC * LC * 8;
    float2* xc  = (float2*)p; p += (size_t)NTOK * INNERC * 8;
    float2* ev  = (float2*)p; p += (size_t)NTOK * INNERC * 8;
    float2* vinv = (float2*)p; p += (size_t)DEPTHC * INNERC * INNERC * 8;
    float2* h0c  = (float2*)p; p += (size_t)DEPTHC * INNERC * 8;

    // prep: inverse (blocks 0..1, hidden) + fp32->fp16 converts (x, w_in, w1, w2, w_out)
    {
        const int n0 = NTOK*VOCABC, n1 = DIMC*VOCABC, n2 = DEPTHC*FFC*DIMC,
                  n3 = DEPTHC*DIMC*FFC, n4 = VOCABC*DIMC;
        int blocks = (n0 + n1 + n2 + n3 + n4) / 1024 + 2;
        k_prep<<<blocks, 256, 0, stream>>>(x, w_in, w1, w2, w_out,
                                           xb, wib, w1b, w2b, wob, n0, n1, n2, n3, n4,
                                           v_re, v_im, h0_re, h0_im, vinv, h0c);
    }

    // in-proj: x @ w_in^T (64x128 tile, split-K=8) -> pbuf; reduction fused into d=0 siogate
    {
        dim3 g(DIMC/128, NTOK/64, 8);
        k_gemmT<64,128,1><<<g, 256, 0, stream>>>(xb, wib, pbuf, nullptr, DIMC, VOCABC, VOCABC/8, NTOK*DIMC);
    }

    for (int d = 0; d < DEPTHC; ++d){
        float* cur = (d == 0) ? h1 : h3;   // reduced layer input (written by siogate)
        float* hb  = h2;                    // sio+residual out
        const float* redBias = (d == 0) ? b_in : (b2 + (d-1)*DIMC);
        const float* redRes  = (d == 0) ? nullptr : h2;
        k_siogate<<<NTOK/4, 128, 0, stream>>>(pbuf, redBias, redRes, cur,
                                              ln1_g + d*DIMC, ln1_b + d*DIMC,
                                              wa + (size_t)d*2*INNERC*DIMC,
                                              wx + (size_t)d*2*INNERC*DIMC, a_t, xc);
        k_scan<<<BC*INNERC, 64, 0, stream>>>(a_t, xc, vinv + d*INNERC*INNERC, h0c + d*INNERC, ev);
        k_siout_ln<<<NTOK, 128, 0, stream>>>(ev, xc, v_re + d*INNERC*INNERC, v_im + d*INNERC*INNERC,
                                             w_ol + (size_t)d*DIMC*INNERC, cur,
                                             ln2_g + d*DIMC, ln2_b + d*DIMC, hb, zb);
        // FFN1: 64x128 tile, silu fused, f16 out
        {
            dim3 g(FFC/128, NTOK/64, 1);
            k_gemmT<64,128,2><<<g, 256, 0, stream>>>(zb, w1b + (size_t)d*FFC*DIMC, ffb, b1 + d*FFC,
                                                     FFC, DIMC, DIMC, 0);
        }
        // FFN2: 64x128 tile, split-K=8 -> pbuf (reduced by next siogate or final red8_ln)
        {
            dim3 g(DIMC/128, NTOK/64, 8);
            k_gemmT<64,128,1><<<g, 256, 0, stream>>>(ffb, w2b + (size_t)d*DIMC*FFC, pbuf, nullptr,
                                                     DIMC, FFC, FFC/8, NTOK*DIMC);
        }
    }
    // final: reduce + residual + LN -> zb (f16)
    k_red8_ln<<<NTOK, 128, 0, stream>>>(pbuf, b2 + (DEPTHC-1)*DIMC, h2, lnl_g, lnl_b, zb, NTOK*DIMC);
    // out = zb @ w_out^T + b_out  (128x128 tile)
    {
        dim3 g(VOCABC/128, NTOK/128, 1);
        k_gemmT<128,128,0><<<g, 256, 0, stream>>>(zb, wob, (float*)d_out, b_out, VOCABC, DIMC, DIMC, 0);
    }
    (void)in_sizes; (void)n_in; (void)out_size; (void)ws_size;
}

// Round 5
// 364.819 us; speedup vs baseline: 1.4658x; 1.0559x over previous
//
#include <hip/hip_runtime.h>
#include <stdint.h>

#define DEPTHC 2
#define DIMC   512
#define FFC    2048
#define INNERC 32
#define VOCABC 8192
#define BC     2
#define LC     512
#define NTOK   1024   // B*L

typedef _Float16 f16;
typedef __attribute__((ext_vector_type(8))) _Float16 f16x8;
typedef __attribute__((ext_vector_type(4))) float f32x4;

__device__ __forceinline__ float2 cmul2(float2 a, float2 b){
    return make_float2(a.x*b.x - a.y*b.y, a.x*b.y + a.y*b.x);
}
__device__ __forceinline__ float2 cadd2(float2 a, float2 b){
    return make_float2(a.x + b.x, a.y + b.y);
}

__device__ __forceinline__ void gl_lds16(const void* g, void* l){
    __builtin_amdgcn_global_load_lds(
        (const __attribute__((address_space(1))) unsigned int*)g,
        (__attribute__((address_space(3))) unsigned int*)l, 16, 0, 0);
}

// ---------------- prep: blocks 0..1 = complex 32x32 inverse; blocks 2.. = fp32->fp16 convert ----
__global__ __launch_bounds__(256) void k_prep(
    const float* __restrict__ s0, const float* __restrict__ s1,
    const float* __restrict__ s2, const float* __restrict__ s3,
    const float* __restrict__ s4,
    f16* __restrict__ d0, f16* __restrict__ d1, f16* __restrict__ d2,
    f16* __restrict__ d3, f16* __restrict__ d4,
    int n0, int n1, int n2, int n3, int n4,
    const float* __restrict__ v_re, const float* __restrict__ v_im,
    const float* __restrict__ h0re, const float* __restrict__ h0im,
    float2* __restrict__ vinv, float2* __restrict__ h0c)
{
    __shared__ float2 M[32][64];
    if (blockIdx.x < 2){
        const int d = blockIdx.x;
        const int tid = threadIdx.x;
        const int c = tid & 63;
        const int wv = tid >> 6;             // 4 waves, rows 8wv..8wv+7
        if (tid < 32) h0c[d*32 + tid] = make_float2(h0re[d*32 + tid], h0im[d*32 + tid]);
#pragma unroll
        for (int rr = 0; rr < 8; ++rr){
            int r = wv*8 + rr;
            float re, im;
            if (c < 32){ re = v_re[d*1024 + r*32 + c]; im = v_im[d*1024 + r*32 + c]; }
            else       { re = (c - 32 == r) ? 1.f : 0.f; im = 0.f; }
            M[r][c] = make_float2(re, im);
        }
        __syncthreads();
#pragma unroll 1
        for (int col = 0; col < 32; ++col){
            float2 prow = M[col][c];                 // pivot row, own column
            float pvx = __shfl(prow.x, col, 64);
            float pvy = __shfl(prow.y, col, 64);
            float dm = pvx*pvx + pvy*pvy;
            float ir = pvx/dm, ii = -pvy/dm;
            float2 nv = make_float2(prow.x*ir - prow.y*ii, prow.x*ii + prow.y*ir);
#pragma unroll
            for (int rr = 0; rr < 8; ++rr){
                int r = wv*8 + rr;
                if (r == col) continue;
                float2 f  = M[r][col];
                float2 m0 = M[r][c];
                m0.x -= f.x*nv.x - f.y*nv.y;
                m0.y -= f.x*nv.y + f.y*nv.x;
                M[r][c] = m0;
            }
            __syncthreads();
        }
        if (c >= 32){
#pragma unroll
            for (int rr = 0; rr < 8; ++rr){
                int r = wv*8 + rr;
                float2 dv = M[r][r];
                float dm = dv.x*dv.x + dv.y*dv.y;
                float ir = dv.x/dm, ii = -dv.y/dm;
                float2 m0 = M[r][c];
                vinv[d*1024 + r*32 + (c - 32)] =
                    make_float2(m0.x*ir - m0.y*ii, m0.x*ii + m0.y*ir);
            }
        }
        return;
    }
    long long i = ((long long)(blockIdx.x - 2) * 256 + threadIdx.x) * 4;
    const float* s; f16* d;
    if (i < n0){ s = s0; d = d0; }
    else { i -= n0;
        if (i < n1){ s = s1; d = d1; }
        else { i -= n1;
            if (i < n2){ s = s2; d = d2; }
            else { i -= n2;
                if (i < n3){ s = s3; d = d3; }
                else { i -= n3; if (i >= n4) return; s = s4; d = d4; }
            }
        }
    }
    float4 v = *(const float4*)(s + i);
    union { f16 h[4]; float2 f2; } u;
    u.h[0] = (f16)v.x; u.h[1] = (f16)v.y; u.h[2] = (f16)v.z; u.h[3] = (f16)v.w;
    *(float2*)(d + i) = u.f2;
}

// ---------------- fp16 MFMA GEMM, MTxNT tile, BK=64, global_load_lds staging ----------------
// C[M,N] = A[M,K] * B[N,K]^T. 4 waves in 2x2; wave tile (MT/2)x(NT/2).
// MODE 0: f32 out = acc + bias[col]; MODE 1: f16 split-K partial; MODE 2: f16 silu(acc+bias)
template<int MT, int NT, int MODE>
__global__ __launch_bounds__(256) void k_gemmT(
    const f16* __restrict__ A, const f16* __restrict__ Bw,
    void* __restrict__ C, const float* __restrict__ bias,
    int N, int K, int klen, int partStride)
{
    constexpr int RM = MT/32, RN = NT/32;
    __shared__ __align__(16) f16 As[MT*64];
    __shared__ __align__(16) f16 Bs[NT*64];
    const int tid = threadIdx.x;
    const int m0 = blockIdx.y * MT;
    const int n0 = blockIdx.x * NT;
    const int kbeg = blockIdx.z * klen;
    const int l = tid & 63;
    const int w = tid >> 6;
    const int fr = l & 15;
    const int fq = l >> 4;
    const int wm = (w >> 1) * (MT/2);
    const int wn = (w & 1) * (NT/2);
    // staging: issue i covers 32 rows; thread t -> row (t>>3), col chunk (t&7)*8 within [rows][64]
    const f16* gA = A  + (size_t)(m0 + (tid >> 3)) * K + kbeg + (tid & 7) * 8;
    const f16* gB = Bw + (size_t)(n0 + (tid >> 3)) * K + kbeg + (tid & 7) * 8;
    const size_t rowskip = (size_t)32 * K;
    f16* lA = As + tid * 8;
    f16* lB = Bs + tid * 8;
    f32x4 acc[RM][RN];
#pragma unroll
    for (int i = 0; i < RM; ++i)
#pragma unroll
        for (int j = 0; j < RN; ++j)
            acc[i][j] = (f32x4){0.f, 0.f, 0.f, 0.f};
    for (int kk = 0; kk < klen; kk += 64){
        __syncthreads();
#pragma unroll
        for (int i = 0; i < MT/32; ++i) gl_lds16(gA + i*rowskip, lA + i*2048);
#pragma unroll
        for (int i = 0; i < NT/32; ++i) gl_lds16(gB + i*rowskip, lB + i*2048);
        gA += 64; gB += 64;
        __syncthreads();
#pragma unroll
        for (int h = 0; h < 2; ++h){
            f16x8 af[RM], bf[RN];
#pragma unroll
            for (int i = 0; i < RM; ++i) af[i] = *(const f16x8*)(As + (wm + 16*i + fr) * 64 + h*32 + fq * 8);
#pragma unroll
            for (int j = 0; j < RN; ++j) bf[j] = *(const f16x8*)(Bs + (wn + 16*j + fr) * 64 + h*32 + fq * 8);
#pragma unroll
            for (int i = 0; i < RM; ++i)
#pragma unroll
                for (int j = 0; j < RN; ++j)
                    acc[i][j] = __builtin_amdgcn_mfma_f32_16x16x32_f16(af[i], bf[j], acc[i][j], 0, 0, 0);
        }
    }
#pragma unroll
    for (int i = 0; i < RM; ++i)
#pragma unroll
        for (int j = 0; j < RN; ++j)
#pragma unroll
            for (int r = 0; r < 4; ++r){
                int row = m0 + wm + 16*i + fq*4 + r;
                int col = n0 + wn + 16*j + fr;
                if (MODE == 1){
                    ((f16*)C + (size_t)blockIdx.z * partStride)[(size_t)row * N + col] = (f16)acc[i][j][r];
                } else if (MODE == 0){
                    ((float*)C)[(size_t)row * N + col] = acc[i][j][r] + bias[col];
                } else {
                    float v = acc[i][j][r] + bias[col];
                    ((f16*)C)[(size_t)row * N + col] = (f16)(v / (1.f + __expf(-v)));
                }
            }
}

// ---------------- wide split-K reduce: out = bias + (res?) + sum_{z<8} part[z] (f16 partials) ----
__global__ __launch_bounds__(256) void k_reduce8(
    float* __restrict__ out, const f16* __restrict__ part,
    const float* __restrict__ bias, const float* __restrict__ res, int n)
{
    int i = (blockIdx.x * 256 + threadIdx.x) * 2;
    if (i >= n) return;
    float v0 = bias[i & (DIMC - 1)], v1 = bias[(i + 1) & (DIMC - 1)];
    if (res){ v0 += res[i]; v1 += res[i + 1]; }
#pragma unroll
    for (int z = 0; z < 8; ++z){
        union { uint32_t u; f16 h[2]; } q;
        q.u = *(const uint32_t*)(part + (size_t)z * n + i);
        v0 += (float)q.h[0]; v1 += (float)q.h[1];
    }
    *(float2*)(out + i) = make_float2(v0, v1);
}

// ---------------- split-K reduce + final LayerNorm -> fp16 (one row/block, f16 partials) --------
__global__ __launch_bounds__(128) void k_red8_ln(
    const f16* __restrict__ part, const float* __restrict__ bias,
    const float* __restrict__ res, const float* __restrict__ g,
    const float* __restrict__ b, f16* __restrict__ out, int n)
{
    int row = blockIdx.x;
    int tid = threadIdx.x;
    __shared__ float sw[2], qw[2];
    float v[4]; float s = 0.f, q = 0.f;
#pragma unroll
    for (int j = 0; j < 4; ++j){
        int c = tid + 128*j;
        int idx = row*DIMC + c;
        float t = bias[c] + res[idx];
#pragma unroll
        for (int z = 0; z < 8; ++z) t += (float)part[(size_t)z * n + idx];
        v[j] = t; s += t; q += t*t;
    }
    for (int off = 32; off; off >>= 1){ s += __shfl_down(s, off, 64); q += __shfl_down(q, off, 64); }
    if ((tid & 63) == 0){ sw[tid >> 6] = s; qw[tid >> 6] = q; }
    __syncthreads();
    float S = sw[0] + sw[1], Q = qw[0] + qw[1];
    float m = S / DIMC;
    float rstd = rsqrtf(Q / DIMC - m*m + 1e-5f);
#pragma unroll
    for (int j = 0; j < 4; ++j){
        int c = tid + 128*j;
        out[(size_t)row*DIMC + c] = (f16)((v[j] - m)*rstd*g[c] + b[c]);
    }
}

// ---------------- fused LN1 + gate projections + gate nonlinearity (reads reduced h) ----------
__global__ __launch_bounds__(128) void k_siogate(
    const float* __restrict__ H, const float* __restrict__ g, const float* __restrict__ b,
    const float* __restrict__ wa, const float* __restrict__ wx,
    float2* __restrict__ a_t, float2* __restrict__ xc)
{
    __shared__ float zs[4][DIMC];
    __shared__ float sc[4][128];
    __shared__ float rs2[2], rq2[2];
    int tid = threadIdx.x;
    int r0 = blockIdx.x * 4;
    for (int gg = 0; gg < 4; ++gg){
        const float* xr = H + (size_t)(r0 + gg) * DIMC;
        float v[4]; float s = 0.f, q = 0.f;
#pragma unroll
        for (int j = 0; j < 4; ++j){ v[j] = xr[tid + 128*j]; s += v[j]; q += v[j]*v[j]; }
        for (int off = 32; off; off >>= 1){ s += __shfl_down(s, off, 64); q += __shfl_down(q, off, 64); }
        if ((tid & 63) == 0){ rs2[tid >> 6] = s; rq2[tid >> 6] = q; }
        __syncthreads();
        float m = (rs2[0] + rs2[1]) / DIMC;
        float var = (rq2[0] + rq2[1]) / DIMC - m*m;
        float rst = rsqrtf(var + 1e-5f);
#pragma unroll
        for (int j = 0; j < 4; ++j){ int c = tid + 128*j; zs[gg][c] = (v[j] - m)*rst*g[c] + b[c]; }
        __syncthreads();
    }
    const float* wrow = (tid < 64) ? (wa + (size_t)tid * DIMC) : (wx + (size_t)(tid - 64) * DIMC);
    float dot[4] = {0.f, 0.f, 0.f, 0.f};
    for (int c = 0; c < DIMC; c += 4){
        float4 wv = *(const float4*)(wrow + c);
#pragma unroll
        for (int gg = 0; gg < 4; ++gg){
            float4 zv = *(const float4*)(&zs[gg][c]);
            dot[gg] += wv.x*zv.x + wv.y*zv.y + wv.z*zv.z + wv.w*zv.w;
        }
    }
#pragma unroll
    for (int gg = 0; gg < 4; ++gg) sc[gg][tid] = dot[gg];
    __syncthreads();
    int gg = tid >> 5, k = tid & 31;
    int row = r0 + gg;
    int bb = row >> 9, t = row & 511;
    float re = sc[gg][2*k], im = sc[gg][2*k + 1];
    float m2 = re*re + im*im;
    float sa = rsqrtf(m2) * (m2 / (1.f + m2));
    a_t[(size_t)(bb*INNERC + k)*LC + t] = make_float2(re*sa, im*sa);
    float xr2 = sc[gg][64 + 2*k], xi2 = sc[gg][64 + 2*k + 1];
    float mx = xr2*xr2 + xi2*xi2;
    float sx = sqrtf(mx);
    xc[(size_t)row*INNERC + k] = make_float2(xr2*sx, xi2*sx);
}

// ---------------- fused wprime + scan: e[t] = a[t]*(e[t-1] + Vinv@xroll[t]) ----------------
__global__ __launch_bounds__(64) void k_scan(
    const float2* __restrict__ a_t, const float2* __restrict__ xc,
    const float2* __restrict__ vinv, const float2* __restrict__ h0c,
    float2* __restrict__ e)
{
    int bk = blockIdx.x;   // b*32 + k
    int l = threadIdx.x;   // 0..63, each owns 8 consecutive t
    int bb = bk >> 5, k = bk & 31;
    float2 vrow[32];
#pragma unroll
    for (int o = 0; o < 32; ++o) vrow[o] = vinv[k*32 + o];
    int base = bk * LC + l * 8;
    float2 av[8], wv[8];
#pragma unroll
    for (int j = 0; j < 8; ++j) av[j] = a_t[base + j];
#pragma unroll
    for (int j = 0; j < 8; ++j){
        int t = l*8 + j;
        const float2* src = (t == 0) ? h0c : (xc + (size_t)(bb*LC + t - 1) * INNERC);
        float2 acc = make_float2(0.f, 0.f);
#pragma unroll
        for (int o = 0; o < 32; o += 2){
            float4 qq = *(const float4*)(src + o);
            acc.x += vrow[o].x*qq.x - vrow[o].y*qq.y;
            acc.y += vrow[o].x*qq.y + vrow[o].y*qq.x;
            acc.x += vrow[o+1].x*qq.z - vrow[o+1].y*qq.w;
            acc.y += vrow[o+1].x*qq.w + vrow[o+1].y*qq.z;
        }
        wv[j] = acc;
    }
    float2 A = make_float2(1.f, 0.f), Bc = make_float2(0.f, 0.f);
#pragma unroll
    for (int j = 0; j < 8; ++j){
        Bc = cmul2(av[j], cadd2(Bc, wv[j]));
        A  = cmul2(av[j], A);
    }
    for (int off = 1; off < 64; off <<= 1){
        float Apx = __shfl_up(A.x,  off, 64), Apy = __shfl_up(A.y,  off, 64);
        float Bpx = __shfl_up(Bc.x, off, 64), Bpy = __shfl_up(Bc.y, off, 64);
        if (l >= off){
            float2 Ap = make_float2(Apx, Apy), Bp = make_float2(Bpx, Bpy);
            Bc = cadd2(cmul2(A, Bp), Bc);
            A  = cmul2(A, Ap);
        }
    }
    float ex = __shfl_up(Bc.x, 1, 64), ey = __shfl_up(Bc.y, 1, 64);
    float2 ecur = (l == 0) ? make_float2(0.f, 0.f) : make_float2(ex, ey);
    size_t obase = ((size_t)bb*LC + l*8) * INNERC + k;
#pragma unroll
    for (int j = 0; j < 8; ++j){
        ecur = cmul2(av[j], cadd2(ecur, wv[j]));
        e[obase + (size_t)j * INNERC] = ecur;
    }
}

// ---------------- hr = Re(V*e)+Re(xc); val = hr@w_ol^T + res; hout=val; zout=LN2(val) f16 ----------------
__global__ __launch_bounds__(128) void k_siout_ln(
    const float2* __restrict__ e, const float2* __restrict__ xc,
    const float* __restrict__ vre, const float* __restrict__ vim,
    const float* __restrict__ wol, const float* __restrict__ res,
    const float* __restrict__ g2, const float* __restrict__ b2,
    float* __restrict__ hout, f16* __restrict__ zout)
{
    int bt = blockIdx.x;
    int tid = threadIdx.x;
    __shared__ float hr[INNERC];
    __shared__ float2 er[INNERC];
    __shared__ float sw[2], qw[2];
    if (tid < 32) er[tid] = e[(size_t)bt*INNERC + tid];
    __syncthreads();
    if (tid < 32){
        const float* vrr = vre + tid*INNERC;
        const float* vir = vim + tid*INNERC;
        float acc = xc[(size_t)bt*INNERC + tid].x;
#pragma unroll
        for (int k2 = 0; k2 < 32; ++k2) acc += vrr[k2]*er[k2].x - vir[k2]*er[k2].y;
        hr[tid] = acc;
    }
    __syncthreads();
    float v[4]; float s = 0.f, q = 0.f;
#pragma unroll
    for (int j = 0; j < 4; ++j){
        int n = tid + 128*j;
        float val = res[(size_t)bt*DIMC + n];
        const float* wr = wol + (size_t)n * INNERC;
#pragma unroll
        for (int i = 0; i < 32; ++i) val += hr[i]*wr[i];
        hout[(size_t)bt*DIMC + n] = val;
        v[j] = val; s += val; q += val*val;
    }
    for (int off = 32; off; off >>= 1){ s += __shfl_down(s, off, 64); q += __shfl_down(q, off, 64); }
    if ((tid & 63) == 0){ sw[tid >> 6] = s; qw[tid >> 6] = q; }
    __syncthreads();
    float S = sw[0] + sw[1], Q = qw[0] + qw[1];
    float m = S / DIMC;
    float rstd = rsqrtf(Q / DIMC - m*m + 1e-5f);
#pragma unroll
    for (int j = 0; j < 4; ++j){
        int n = tid + 128*j;
        zout[(size_t)bt*DIMC + n] = (f16)((v[j] - m)*rstd*g2[n] + b2[n]);
    }
}

extern "C" void kernel_launch(void* const* d_in, const int* in_sizes, int n_in,
                              void* d_out, int out_size, void* d_ws, size_t ws_size,
                              hipStream_t stream)
{
    const float* x     = (const float*)d_in[0];
    const float* w_in  = (const float*)d_in[1];
    const float* b_in  = (const float*)d_in[2];
    const float* ln1_g = (const float*)d_in[3];
    const float* ln1_b = (const float*)d_in[4];
    const float* wa    = (const float*)d_in[5];
    const float* wx    = (const float*)d_in[6];
    const float* v_re  = (const float*)d_in[7];
    const float* v_im  = (const float*)d_in[8];
    const float* h0_re = (const float*)d_in[9];
    const float* h0_im = (const float*)d_in[10];
    const float* w_ol  = (const float*)d_in[11];
    const float* ln2_g = (const float*)d_in[12];
    const float* ln2_b = (const float*)d_in[13];
    const float* w1    = (const float*)d_in[14];
    const float* b1    = (const float*)d_in[15];
    const float* w2    = (const float*)d_in[16];
    const float* b2    = (const float*)d_in[17];
    const float* lnl_g = (const float*)d_in[18];
    const float* lnl_b = (const float*)d_in[19];
    const float* w_out = (const float*)d_in[20];
    const float* b_out = (const float*)d_in[21];

    char* p = (char*)d_ws;
    f16* xb   = (f16*)p;   p += (size_t)NTOK * VOCABC * 2;
    f16* wib  = (f16*)p;   p += (size_t)DIMC * VOCABC * 2;
    f16* wob  = (f16*)p;   p += (size_t)VOCABC * DIMC * 2;
    f16* w1b  = (f16*)p;   p += (size_t)DEPTHC * FFC * DIMC * 2;
    f16* w2b  = (f16*)p;   p += (size_t)DEPTHC * DIMC * FFC * 2;
    float* h1 = (float*)p; p += (size_t)NTOK * DIMC * 4;
    float* h2 = (float*)p; p += (size_t)NTOK * DIMC * 4;
    float* h3 = (float*)p; p += (size_t)NTOK * DIMC * 4;
    f16* zb   = (f16*)p;   p += (size_t)NTOK * DIMC * 2;
    f16* ffb  = (f16*)p;   p += (size_t)NTOK * FFC * 2;
    f16* pbuf = (f16*)p;   p += (size_t)8 * NTOK * DIMC * 2;
    float2* a_t = (float2*)p; p += (size_t)BC * INNERC * LC * 8;
    float2* xc  = (float2*)p; p += (size_t)NTOK * INNERC * 8;
    float2* ev  = (float2*)p; p += (size_t)NTOK * INNERC * 8;
    float2* vinv = (float2*)p; p += (size_t)DEPTHC * INNERC * INNERC * 8;
    float2* h0c  = (float2*)p; p += (size_t)DEPTHC * INNERC * 8;

    // prep: inverse (blocks 0..1, hidden) + fp32->fp16 converts (x, w_in, w1, w2, w_out)
    {
        const int n0 = NTOK*VOCABC, n1 = DIMC*VOCABC, n2 = DEPTHC*FFC*DIMC,
                  n3 = DEPTHC*DIMC*FFC, n4 = VOCABC*DIMC;
        int blocks = (n0 + n1 + n2 + n3 + n4) / 1024 + 2;
        k_prep<<<blocks, 256, 0, stream>>>(x, w_in, w1, w2, w_out,
                                           xb, wib, w1b, w2b, wob, n0, n1, n2, n3, n4,
                                           v_re, v_im, h0_re, h0_im, vinv, h0c);
    }

    // in-proj: x @ w_in^T (64x128 tile, split-K=8, f16 partials)
    {
        dim3 g(DIMC/128, NTOK/64, 8);
        k_gemmT<64,128,1><<<g, 256, 0, stream>>>(xb, wib, pbuf, nullptr, DIMC, VOCABC, VOCABC/8, NTOK*DIMC);
    }

    for (int d = 0; d < DEPTHC; ++d){
        float* cur = (d == 0) ? h1 : h3;   // layer input (reduced)
        float* hb  = h2;                    // sio+residual out
        const float* redBias = (d == 0) ? b_in : (b2 + (d-1)*DIMC);
        const float* redRes  = (d == 0) ? nullptr : h2;
        k_reduce8<<<(NTOK*DIMC)/512, 256, 0, stream>>>(cur, pbuf, redBias, redRes, NTOK*DIMC);
        k_siogate<<<NTOK/4, 128, 0, stream>>>(cur, ln1_g + d*DIMC, ln1_b + d*DIMC,
                                              wa + (size_t)d*2*INNERC*DIMC,
                                              wx + (size_t)d*2*INNERC*DIMC, a_t, xc);
        k_scan<<<BC*INNERC, 64, 0, stream>>>(a_t, xc, vinv + d*INNERC*INNERC, h0c + d*INNERC, ev);
        k_siout_ln<<<NTOK, 128, 0, stream>>>(ev, xc, v_re + d*INNERC*INNERC, v_im + d*INNERC*INNERC,
                                             w_ol + (size_t)d*DIMC*INNERC, cur,
                                             ln2_g + d*DIMC, ln2_b + d*DIMC, hb, zb);
        // FFN1: 64x128 tile, silu fused, f16 out
        {
            dim3 g(FFC/128, NTOK/64, 1);
            k_gemmT<64,128,2><<<g, 256, 0, stream>>>(zb, w1b + (size_t)d*FFC*DIMC, ffb, b1 + d*FFC,
                                                     FFC, DIMC, DIMC, 0);
        }
        // FFN2: 64x128 tile, split-K=8, f16 partials
        {
            dim3 g(DIMC/128, NTOK/64, 8);
            k_gemmT<64,128,1><<<g, 256, 0, stream>>>(ffb, w2b + (size_t)d*DIMC*FFC, pbuf, nullptr,
                                                     DIMC, FFC, FFC/8, NTOK*DIMC);
        }
    }
    // final: reduce + residual + LN -> zb (f16)
    k_red8_ln<<<NTOK, 128, 0, stream>>>(pbuf, b2 + (DEPTHC-1)*DIMC, h2, lnl_g, lnl_b, zb, NTOK*DIMC);
    // out = zb @ w_out^T + b_out  (128x128 tile)
    {
        dim3 g(VOCABC/128, NTOK/128, 1);
        k_gemmT<128,128,0><<<g, 256, 0, stream>>>(zb, wob, (float*)d_out, b_out, VOCABC, DIMC, DIMC, 0);
    }
    (void)in_sizes; (void)n_in; (void)out_size; (void)ws_size;
}